// Round 1
// 222.294 us; speedup vs baseline: 1.0045x; 1.0045x over previous
//
#include <hip/hip_runtime.h>
#include <hip/hip_bf16.h>
#include <stdint.h>

// Problem constants
#define B_   2
#define T_   2048
#define D_   1024
#define H_   16
#define HD_  64
#define MEM_ 512
#define KV_  (MEM_ + T_)   // 2560
#define NIT_ (KV_ / 64)    // 40 kv-tiles of 64

using bf16 = __bf16;
typedef __bf16 bf16x8 __attribute__((ext_vector_type(8)));
typedef float  f32x4  __attribute__((ext_vector_type(4)));
typedef short  s16x4  __attribute__((ext_vector_type(4)));

__device__ __forceinline__ f32x4 mfma16(bf16x8 a, bf16x8 b, f32x4 c) {
  return __builtin_amdgcn_mfma_f32_16x16x32_bf16(a, b, c, 0, 0, 0);
}
__device__ __forceinline__ f32x4 mfma16k16(s16x4 a, s16x4 b, f32x4 c) {
  return __builtin_amdgcn_mfma_f32_16x16x16bf16_1k(a, b, c, 0, 0, 0);
}

// Async global->LDS, 16B per lane. LDS dest is wave-uniform base + lane*16,
// so callers pass &lds[tid*16] with lane-contiguous tids (linear layout).
__device__ __forceinline__ void gll16(const void* g, void* l) {
  __builtin_amdgcn_global_load_lds(
      (const __attribute__((address_space(1))) unsigned int*)g,
      (__attribute__((address_space(3))) unsigned int*)l, 16, 0, 0);
}

__device__ __forceinline__ unsigned short bf16_bits(float f) {
  bf16 h = (bf16)f;
  return __builtin_bit_cast(unsigned short, h);
}

__device__ __forceinline__ ushort4 pack4(f32x4 v) {
  ushort4 p;
  p.x = bf16_bits(v[0]); p.y = bf16_bits(v[1]);
  p.z = bf16_bits(v[2]); p.w = bf16_bits(v[3]);
  return p;
}

// ---------------------------------------------------------------------------
// conv: f32 -> bf16, 8 elems/thread, exact-size grids (no bounds check).
// ---------------------------------------------------------------------------
__global__ void conv_bf16(const float* __restrict__ s, bf16* __restrict__ d) {
  size_t i = ((size_t)blockIdx.x * 256 + threadIdx.x) * 8;
  f32x4 a = *(const f32x4*)(s + i);
  f32x4 b = *(const f32x4*)(s + i + 4);
  bf16x8 r;
  r[0] = (bf16)a[0]; r[1] = (bf16)a[1]; r[2] = (bf16)a[2]; r[3] = (bf16)a[3];
  r[4] = (bf16)b[0]; r[5] = (bf16)b[1]; r[6] = (bf16)b[2]; r[7] = (bf16)b[3];
  *(bf16x8*)(d + i) = r;
}

// ---------------------------------------------------------------------------
// fill: memory [512][1024] f32 -> mem_k bf16 per-head plane [16][512][64]
//       and mem_vt bf16 [1024][512] (transposed).
// ---------------------------------------------------------------------------
__global__ void fill_mem(const float* __restrict__ memory,
                         bf16* __restrict__ mem_k, bf16* __restrict__ mem_vt) {
  int idx = blockIdx.x * 256 + threadIdx.x;   // [0, 512*1024)
  int m = idx >> 10, d = idx & 1023;
  int hh = d >> 6, hd = d & 63;
  bf16 v = (bf16)memory[idx];
  mem_k[((size_t)hh * MEM_ + m) * HD_ + hd] = v;   // per-head plane
  mem_vt[(size_t)d * MEM_ + m] = v;
}

// ---------------------------------------------------------------------------
// GEMM (B^T form): C[M,N] = A[M,K] * W[N,K]^T.  128x128 tile, BK=32,
// 4 waves (2x2 of 64x64).  bf16 inputs only; staging via global_load_lds
// (width 16) into linear [128][32] LDS tiles.  LDS-read bank conflicts are
// removed by XOR-ing the 16B k-chunk with (row>>1)&3, applied on BOTH the
// pre-swizzled global source chunk and the ds_read address (both-sides rule).
// EPI==0: scatter q/k -> [bh][t][64], v -> vt_ws[bh][hd][t] (transposed).
// EPI==1: bias add -> Cout [M][1024] f32.  APLANE: A is plane layout
//         [bh][t][64] (logical row m=b*T+t, col d=h*64+hd).
// ---------------------------------------------------------------------------
template <int EPI, bool APLANE>
__global__ __launch_bounds__(256) void gemm_bt(
    const bf16* __restrict__ A, const bf16* __restrict__ W,
    const float* __restrict__ bias,
    bf16* __restrict__ q_ws, bf16* __restrict__ k_ws, bf16* __restrict__ vt_ws,
    float* __restrict__ Cout, int K) {
  __shared__ __align__(16) bf16 Als[128 * 32];
  __shared__ __align__(16) bf16 Bls[128 * 32];
  char* AB = (char*)Als;
  char* BB = (char*)Bls;
  const int m0 = blockIdx.y * 128;
  const int n0 = blockIdx.x * 128;
  const int tid = threadIdx.x;
  const int w = tid >> 6;
  const int lane = tid & 63;
  const int lx = lane & 15;
  const int quad = lane >> 4;
  const int amb = (w & 1) * 64;
  const int bnb = (w >> 1) * 64;
  const int r0 = tid >> 2;                       // staging row 0..63
  const int cs = (tid & 3) ^ ((tid >> 3) & 3);   // pre-swizzled k-chunk
  const int rsw = (lx >> 1) & 3;                 // read-side swizzle key

  f32x4 acc[4][4];
#pragma unroll
  for (int i = 0; i < 4; i++)
#pragma unroll
    for (int j = 0; j < 4; j++) acc[i][j] = (f32x4){0.f, 0.f, 0.f, 0.f};

  for (int k0 = 0; k0 < K; k0 += 32) {
    const bf16 *pa0, *pa1;
    if constexpr (APLANE) {
      // row m -> (b,t); swizzled col chunk stays within one h (32 | 64)
      int c0 = k0 + cs * 8, hh = c0 >> 6, hd = c0 & 63;
      int mA = m0 + r0, mB = mA + 64;
      pa0 = A + ((size_t)((mA >> 11) * H_ + hh) * T_ + (mA & 2047)) * HD_ + hd;
      pa1 = A + ((size_t)((mB >> 11) * H_ + hh) * T_ + (mB & 2047)) * HD_ + hd;
    } else {
      pa0 = A + (size_t)(m0 + r0) * K + k0 + cs * 8;
      pa1 = pa0 + (size_t)64 * K;
    }
    const bf16* pb0 = W + (size_t)(n0 + r0) * K + k0 + cs * 8;
    const bf16* pb1 = pb0 + (size_t)64 * K;

    __syncthreads();   // prev iteration's LDS reads done
    gll16(pa0, AB + tid * 16);
    gll16(pa1, AB + tid * 16 + 4096);
    gll16(pb0, BB + tid * 16);
    gll16(pb1, BB + tid * 16 + 4096);
    __syncthreads();   // drains vmcnt -> tiles valid

    bf16x8 af[4], bfr[4];
#pragma unroll
    for (int mt = 0; mt < 4; mt++)
      af[mt] = *(const bf16x8*)(AB + (size_t)(amb + mt * 16 + lx) * 64 +
                                ((quad ^ rsw) * 16));
#pragma unroll
    for (int nt = 0; nt < 4; nt++)
      bfr[nt] = *(const bf16x8*)(BB + (size_t)(bnb + nt * 16 + lx) * 64 +
                                 ((quad ^ rsw) * 16));
#pragma unroll
    for (int mt = 0; mt < 4; mt++)
#pragma unroll
      for (int nt = 0; nt < 4; nt++)
        acc[mt][nt] = mfma16(af[mt], bfr[nt], acc[mt][nt]);
  }

  // Epilogue. C/D layout: row = quad*4+reg (m), col = lane&15 (n).
  if (EPI == 0) {
#pragma unroll
    for (int mt = 0; mt < 4; mt++) {
      int mbase = m0 + amb + mt * 16 + quad * 4;
      int b = mbase >> 11;        // T=2048
      int t = mbase & 2047;
#pragma unroll
      for (int nt = 0; nt < 4; nt++) {
        int col = n0 + bnb + nt * 16 + lx;     // [0,3072)
        int which = col >> 10;                 // 0=q 1=k 2=v
        int d = col & 1023;
        int hh = d >> 6, hdi = d & 63;
        int bh = b * H_ + hh;
        if (which == 0) {
#pragma unroll
          for (int r = 0; r < 4; r++)
            q_ws[((size_t)bh * T_ + t + r) * HD_ + hdi] = (bf16)acc[mt][nt][r];
        } else if (which == 1) {
#pragma unroll
          for (int r = 0; r < 4; r++)
            k_ws[((size_t)bh * T_ + t + r) * HD_ + hdi] = (bf16)acc[mt][nt][r];
        } else {
          // v^T: 4 consecutive t -> one 8B store
          *(ushort4*)&vt_ws[((size_t)bh * HD_ + hdi) * T_ + t] =
              pack4(acc[mt][nt]);
        }
      }
    }
  } else {
#pragma unroll
    for (int nt = 0; nt < 4; nt++) {
      int col = n0 + bnb + nt * 16 + lx;
      float bias_f = bias[col];
#pragma unroll
      for (int mt = 0; mt < 4; mt++) {
        int mbase = m0 + amb + mt * 16 + quad * 4;
#pragma unroll
        for (int r = 0; r < 4; r++)
          Cout[(size_t)(mbase + r) * D_ + col] = acc[mt][nt][r] + bias_f;
      }
    }
  }
}

// ---------------------------------------------------------------------------
// Flash attention.  Same 4-wave/128q/2qg structure as R5, with:
//  * linear [64][64] K/V LDS tiles + byte^=((row&7)<<4) XOR swizzle
//    (kills the pad-72 additive bank-conflict pattern: K b128 reads become
//    conflict-free, V b64 reads a uniform free 2-way),
//  * global_load_lds staging with PRE-SWIZZLED global source chunks
//    (LDS dest stays linear per the gll lane-ordering rule),
//  * exp2 diet: Q pre-scaled by 0.125*log2(e).
// 1 block = 128 q of one (b,h); kv-tile 64; grid 512; output in-place q_ws.
// ---------------------------------------------------------------------------
__global__ __launch_bounds__(256, 2) void attn_kernel(
    bf16* __restrict__ q_ws, const bf16* __restrict__ k_ws,
    const bf16* __restrict__ vt_ws, const bf16* __restrict__ mem_k,
    const bf16* __restrict__ mem_vt) {
  __shared__ __align__(16) bf16 Kls[64 * 64];
  __shared__ __align__(16) bf16 Vls[64 * 64];
  char* KB = (char*)Kls;
  char* VB = (char*)Vls;
  const int tid = threadIdx.x;
  const int w = tid >> 6;
  const int lane = tid & 63;
  const int lx = lane & 15;
  const int quad = lane >> 4;
  const int bh = blockIdx.x & 31;      // XCD-locality
  const int qt = blockIdx.x >> 5;      // 16 q-tiles of 128
  const int q0 = qt * 128 + w * 32;
  const int h = bh & 15;

  const int srow1 = tid >> 3;              // 0..31
  const int sc1 = (tid & 7) ^ (srow1 & 7); // pre-swizzled source chunk
  // rows srow1+32 share (row&7) -> same swizzled chunk

  bf16* qbase = q_ws + ((size_t)bh * T_ + q0) * HD_;

  // Q B-frags (k32); fold softmax scale AND log2(e) into Q.
  const float QSCALE = 0.125f * 1.44269504089f;
  bf16x8 qf[2][2];
#pragma unroll
  for (int qg = 0; qg < 2; qg++)
#pragma unroll
    for (int hf = 0; hf < 2; hf++) {
      bf16x8 v = *(const bf16x8*)(qbase + (size_t)(qg * 16 + lx) * HD_ +
                                  hf * 32 + quad * 8);
#pragma unroll
      for (int i = 0; i < 8; i++)
        v[i] = (bf16)((float)v[i] * QSCALE);
      qf[qg][hf] = v;
    }

  const bf16* kpl = k_ws + (size_t)bh * T_ * HD_;
  const bf16* vpl = vt_ws + (size_t)bh * HD_ * T_;
  const bf16* mkp = mem_k + (size_t)h * MEM_ * HD_;   // per-head plane
  const bf16* mvp = mem_vt + (size_t)h * HD_ * MEM_;

  f32x4 o[4][2];
#pragma unroll
  for (int mt = 0; mt < 4; mt++)
#pragma unroll
    for (int qg = 0; qg < 2; qg++) o[mt][qg] = (f32x4){0.f, 0.f, 0.f, 0.f};
  float lsum[2] = {0.f, 0.f};

  for (int it = 0; it < NIT_; it++) {
    const int kv0 = it * 64;
    const bf16 *kp1, *kp2, *vp1, *vp2;
    if (kv0 < MEM_) {
      kp1 = mkp + (size_t)(kv0 + srow1) * HD_ + sc1 * 8;
      kp2 = kp1 + (size_t)32 * HD_;
      vp1 = mvp + (size_t)srow1 * MEM_ + kv0 + sc1 * 8;
      vp2 = vp1 + (size_t)32 * MEM_;
    } else {
      const int t0 = kv0 - MEM_;
      kp1 = kpl + (size_t)(t0 + srow1) * HD_ + sc1 * 8;
      kp2 = kp1 + (size_t)32 * HD_;
      vp1 = vpl + (size_t)srow1 * T_ + t0 + sc1 * 8;
      vp2 = vp1 + (size_t)32 * T_;
    }
    __syncthreads();   // prev tile's LDS reads done
    gll16(kp1, KB + tid * 16);
    gll16(kp2, KB + tid * 16 + 4096);
    gll16(vp1, VB + tid * 16);
    gll16(vp2, VB + tid * 16 + 4096);
    __syncthreads();   // vmcnt drained -> tiles valid

    const int sw = (lx & 7) << 4;   // read-side swizzle (row&7 == lx&7)
    f32x4 s[4][2];
#pragma unroll
    for (int g = 0; g < 4; g++) {
      const char* kb = KB + (size_t)(g * 16 + lx) * 128;
      bf16x8 ka0 = *(const bf16x8*)(kb + ((quad * 16) ^ sw));
      bf16x8 ka1 = *(const bf16x8*)(kb + ((64 + quad * 16) ^ sw));
#pragma unroll
      for (int qg = 0; qg < 2; qg++) {
        s[g][qg] = (f32x4){0.f, 0.f, 0.f, 0.f};
        s[g][qg] = mfma16(ka0, qf[qg][0], s[g][qg]);
        s[g][qg] = mfma16(ka1, qf[qg][1], s[g][qg]);
      }
    }

    s16x4 pb[2][4];
#pragma unroll
    for (int qg = 0; qg < 2; qg++) {
      float ps = 0.f;
#pragma unroll
      for (int g = 0; g < 4; g++) {
#pragma unroll
        for (int r = 0; r < 4; r++) {
          float p = __builtin_amdgcn_exp2f(s[g][qg][r]);  // raw v_exp_f32
          ps += p;
          pb[qg][g][r] = (short)bf16_bits(p);
        }
      }
      lsum[qg] += ps;
    }

#pragma unroll
    for (int mt = 0; mt < 4; mt++) {
      const char* vb = VB + (size_t)(mt * 16 + lx) * 128;
#pragma unroll
      for (int kk = 0; kk < 4; kk++) {
        s16x4 va = *(const s16x4*)(vb + ((kk * 32 + quad * 8) ^ sw));
#pragma unroll
        for (int qg = 0; qg < 2; qg++)
          o[mt][qg] = mfma16k16(va, pb[qg][kk], o[mt][qg]);
      }
    }
  }

  float inv[2];
#pragma unroll
  for (int qg = 0; qg < 2; qg++) {
    float s2 = lsum[qg];
    s2 += __shfl_xor(s2, 16);
    s2 += __shfl_xor(s2, 32);
    inv[qg] = 1.f / s2;
  }

#pragma unroll
  for (int qg = 0; qg < 2; qg++) {
#pragma unroll
    for (int mt = 0; mt < 4; mt++) {
      f32x4 ov;
#pragma unroll
      for (int r = 0; r < 4; r++) ov[r] = o[mt][qg][r] * inv[qg];
      *(ushort4*)(qbase + (size_t)(qg * 16 + lx) * HD_ + mt * 16 + quad * 4)
          = pack4(ov);
    }
  }
}

// ---------------------------------------------------------------------------
// Scratch plan (ws stays 26 MiB, as before):
//   ws:    q_ws 0-8M | k_ws 8-16M | vt_ws 16-24M | mem_k 24-25M | mem_vt 25-26M
//   d_out: xb (bf16 x) 0-8M | wqb (bf16 w_qkv) 8-14M   [dead after gemm1;
//          gemm2 overwrites all of d_out with the real output]
//   wob (bf16 w_out) lands in k_ws space AFTER attn (k_ws dead by then).
// ---------------------------------------------------------------------------
extern "C" void kernel_launch(void* const* d_in, const int* in_sizes, int n_in,
                              void* d_out, int out_size, void* d_ws,
                              size_t ws_size, hipStream_t stream) {
  const float* x      = (const float*)d_in[0];   // [B,T,D]   f32
  const float* w_qkv  = (const float*)d_in[1];   // [3D,D]    f32
  const float* w_out  = (const float*)d_in[2];   // [D,D]     f32
  const float* b_out  = (const float*)d_in[3];   // [D]       f32
  const float* memory = (const float*)d_in[4];   // [MEM,D]   f32

  char* ws = (char*)d_ws;
  bf16* q_ws   = (bf16*)(ws);                    // [32][2048][64]  8 MiB
  bf16* k_ws   = (bf16*)(ws + (8u << 20));       // [32][2048][64]  8 MiB
  bf16* vt_ws  = (bf16*)(ws + (16u << 20));      // [32][64][2048]  8 MiB
  bf16* mem_k  = (bf16*)(ws + (24u << 20));      // [16][512][64]   1 MiB
  bf16* mem_vt = (bf16*)(ws + (25u << 20));      // [1024][512]     1 MiB
  float* out = (float*)d_out;                    // f32 per reference

  char* outc = (char*)d_out;
  bf16* xb  = (bf16*)(outc);                     // 8 MiB scratch in d_out
  bf16* wqb = (bf16*)(outc + (8u << 20));        // 6 MiB scratch in d_out
  bf16* wob = (bf16*)(ws + (8u << 20));          // reuses k_ws (dead post-attn)

  conv_bf16<<<dim3(2048), dim3(256), 0, stream>>>(x, xb);
  conv_bf16<<<dim3(1536), dim3(256), 0, stream>>>(w_qkv, wqb);
  fill_mem<<<dim3(2048), dim3(256), 0, stream>>>(memory, mem_k, mem_vt);
  gemm_bt<0, false><<<dim3(24, 32), dim3(256), 0, stream>>>(
      xb, wqb, nullptr, q_ws, k_ws, vt_ws, nullptr, 1024);
  attn_kernel<<<dim3(512), dim3(256), 0, stream>>>(
      q_ws, k_ws, vt_ws, mem_k, mem_vt);
  conv_bf16<<<dim3(512), dim3(256), 0, stream>>>(w_out, wob);
  gemm_bt<1, true><<<dim3(8, 32), dim3(256), 0, stream>>>(
      q_ws, wob, b_out, nullptr, nullptr, nullptr, out, 1024);
}

// Round 2
// 212.778 us; speedup vs baseline: 1.0494x; 1.0447x over previous
//
#include <hip/hip_runtime.h>
#include <hip/hip_bf16.h>
#include <stdint.h>

// Problem constants
#define B_   2
#define T_   2048
#define D_   1024
#define H_   16
#define HD_  64
#define MEM_ 512
#define KV_  (MEM_ + T_)   // 2560
#define NIT_ (KV_ / 64)    // 40 kv-tiles of 64

using bf16 = __bf16;
typedef __bf16 bf16x8 __attribute__((ext_vector_type(8)));
typedef float  f32x4  __attribute__((ext_vector_type(4)));
typedef short  s16x4  __attribute__((ext_vector_type(4)));

__device__ __forceinline__ f32x4 mfma16(bf16x8 a, bf16x8 b, f32x4 c) {
  return __builtin_amdgcn_mfma_f32_16x16x32_bf16(a, b, c, 0, 0, 0);
}
__device__ __forceinline__ f32x4 mfma16k16(s16x4 a, s16x4 b, f32x4 c) {
  return __builtin_amdgcn_mfma_f32_16x16x16bf16_1k(a, b, c, 0, 0, 0);
}

// Async global->LDS, 16B per lane (dest = wave-uniform base + lane*16).
__device__ __forceinline__ void gll16(const void* g, void* l) {
  __builtin_amdgcn_global_load_lds(
      (const __attribute__((address_space(1))) unsigned int*)g,
      (__attribute__((address_space(3))) unsigned int*)l, 16, 0, 0);
}

__device__ __forceinline__ unsigned short bf16_bits(float f) {
  bf16 h = (bf16)f;
  return __builtin_bit_cast(unsigned short, h);
}

__device__ __forceinline__ ushort4 pack4(f32x4 v) {
  ushort4 p;
  p.x = bf16_bits(v[0]); p.y = bf16_bits(v[1]);
  p.z = bf16_bits(v[2]); p.w = bf16_bits(v[3]);
  return p;
}

__device__ __forceinline__ bf16x8 cvt8(f32x4 a, f32x4 b) {
  bf16x8 r;
  r[0] = (bf16)a[0]; r[1] = (bf16)a[1]; r[2] = (bf16)a[2]; r[3] = (bf16)a[3];
  r[4] = (bf16)b[0]; r[5] = (bf16)b[1]; r[6] = (bf16)b[2]; r[7] = (bf16)b[3];
  return r;
}

// ---------------------------------------------------------------------------
// prep (fused): x conv (2048 blk) | w_qkv conv (1536 blk) | fill_mem (256 blk)
// fill: memory [512][1024] f32 -> mem_k per-head plane [16][512][64] and
//       mem_vt [1024][512] (transposed).
// ---------------------------------------------------------------------------
__global__ void prep(const float* __restrict__ x, const float* __restrict__ wq,
                     const float* __restrict__ memory,
                     bf16* __restrict__ xb, bf16* __restrict__ wqb,
                     bf16* __restrict__ mem_k, bf16* __restrict__ mem_vt) {
  int blk = blockIdx.x;
  if (blk < 3584) {
    const float* s = (blk < 2048) ? x : wq;
    bf16* d = (blk < 2048) ? xb : wqb;
    size_t i = ((size_t)(blk < 2048 ? blk : blk - 2048) * 256 + threadIdx.x) * 8;
    f32x4 a = *(const f32x4*)(s + i);
    f32x4 b = *(const f32x4*)(s + i + 4);
    *(bf16x8*)(d + i) = cvt8(a, b);
  } else {
    int idx8 = ((blk - 3584) * 256 + threadIdx.x) * 8;   // [0, 512*1024)
    int m = idx8 >> 10, d0 = idx8 & 1023;
    int hh = d0 >> 6, hd0 = d0 & 63;
    f32x4 a = *(const f32x4*)(memory + idx8);
    f32x4 b = *(const f32x4*)(memory + idx8 + 4);
    bf16x8 r = cvt8(a, b);
    *(bf16x8*)&mem_k[((size_t)hh * MEM_ + m) * HD_ + hd0] = r;
#pragma unroll
    for (int j = 0; j < 8; j++)
      mem_vt[(size_t)(d0 + j) * MEM_ + m] = r[j];
  }
}

// w_out conv: runs AFTER attn (dest aliases k_ws, dead by then).
__global__ void conv_bf16(const float* __restrict__ s, bf16* __restrict__ d) {
  size_t i = ((size_t)blockIdx.x * 256 + threadIdx.x) * 8;
  f32x4 a = *(const f32x4*)(s + i);
  f32x4 b = *(const f32x4*)(s + i + 4);
  *(bf16x8*)(d + i) = cvt8(a, b);
}

// ---------------------------------------------------------------------------
// GEMM (B^T form): C[M,N] = A[M,K] * W[N,K]^T.  128 x NTILE tile, BK=64
// (m97 config: 32 MFMA per barrier pair), 4 waves (2x2).  Staging via
// global_load_lds w16 into linear [rows][64] LDS; 16B-chunk XOR swizzle
// p = l ^ (row&7) applied on BOTH source chunk and ds_read (both-sides rule).
// EPI==0: scatter q/k -> [bh][t][64], v -> vt_ws[bh][hd][t] (transposed).
// EPI==1: bias add -> Cout [M][1024] f32.  APLANE: A is plane layout
//         [bh][t][64] (logical row m=b*T+t, col d=h*64+hd).
// ---------------------------------------------------------------------------
template <int EPI, bool APLANE, int NTILE>
__global__ __launch_bounds__(256) void gemm_bt(
    const bf16* __restrict__ A, const bf16* __restrict__ W,
    const float* __restrict__ bias,
    bf16* __restrict__ q_ws, bf16* __restrict__ k_ws, bf16* __restrict__ vt_ws,
    float* __restrict__ Cout, int K) {
  constexpr int NF = NTILE / 32;        // n-frags per wave
  constexpr int NB = NTILE / 32;        // B-tile gll count
  __shared__ __align__(16) bf16 Als[128 * 64];
  __shared__ __align__(16) bf16 Bls[NTILE * 64];
  char* AB = (char*)Als;
  char* BB = (char*)Bls;
  const int m0 = blockIdx.y * 128;
  const int n0 = blockIdx.x * NTILE;
  const int tid = threadIdx.x;
  const int w = tid >> 6;
  const int lane = tid & 63;
  const int lx = lane & 15;
  const int quad = lane >> 4;
  const int amb = (w & 1) * 64;
  const int bnb = (w >> 1) * (NTILE / 2);
  const int srow = tid >> 3;                        // 0..31 (+32g per gll)
  const int cs = (tid & 7) ^ (srow & 7);            // swizzled source chunk

  f32x4 acc[4][NF];
#pragma unroll
  for (int i = 0; i < 4; i++)
#pragma unroll
    for (int j = 0; j < NF; j++) acc[i][j] = (f32x4){0.f, 0.f, 0.f, 0.f};

  for (int k0 = 0; k0 < K; k0 += 64) {
    const bf16* pa[4];
#pragma unroll
    for (int g = 0; g < 4; g++) {
      int r = srow + 32 * g;
      if constexpr (APLANE) {
        int hh = k0 >> 6, hd = cs * 8;
        int mA = m0 + r;
        pa[g] = A + ((size_t)((mA >> 11) * H_ + hh) * T_ + (mA & 2047)) * HD_ + hd;
      } else {
        pa[g] = A + (size_t)(m0 + r) * K + k0 + cs * 8;
      }
    }
    const bf16* pb[NB];
#pragma unroll
    for (int g = 0; g < NB; g++)
      pb[g] = W + (size_t)(n0 + srow + 32 * g) * K + k0 + cs * 8;

    __syncthreads();   // prev iteration's LDS reads done
#pragma unroll
    for (int g = 0; g < 4; g++) gll16(pa[g], AB + g * 4096 + tid * 16);
#pragma unroll
    for (int g = 0; g < NB; g++) gll16(pb[g], BB + g * 4096 + tid * 16);
    __syncthreads();   // drains vmcnt -> tiles valid

    bf16x8 af[4][2], bfr[NF][2];
    const int rk = (lx & 7) << 4;   // read-side swizzle key (row&7 == lx&7)
#pragma unroll
    for (int mt = 0; mt < 4; mt++)
#pragma unroll
      for (int kh = 0; kh < 2; kh++)
        af[mt][kh] = *(const bf16x8*)(AB + (size_t)(amb + mt * 16 + lx) * 128 +
                                      ((quad * 16 + kh * 64) ^ rk));
#pragma unroll
    for (int nt = 0; nt < NF; nt++)
#pragma unroll
      for (int kh = 0; kh < 2; kh++)
        bfr[nt][kh] = *(const bf16x8*)(BB + (size_t)(bnb + nt * 16 + lx) * 128 +
                                       ((quad * 16 + kh * 64) ^ rk));
#pragma unroll
    for (int kh = 0; kh < 2; kh++)
#pragma unroll
      for (int mt = 0; mt < 4; mt++)
#pragma unroll
        for (int nt = 0; nt < NF; nt++)
          acc[mt][nt] = mfma16(af[mt][kh], bfr[nt][kh], acc[mt][nt]);
  }

  // Epilogue. C/D layout: row = quad*4+reg (m), col = lane&15 (n).
  if (EPI == 0) {
#pragma unroll
    for (int mt = 0; mt < 4; mt++) {
      int mbase = m0 + amb + mt * 16 + quad * 4;
      int b = mbase >> 11;        // T=2048
      int t = mbase & 2047;
#pragma unroll
      for (int nt = 0; nt < NF; nt++) {
        int col = n0 + bnb + nt * 16 + lx;     // [0,3072)
        int which = col >> 10;                 // 0=q 1=k 2=v
        int d = col & 1023;
        int hh = d >> 6, hdi = d & 63;
        int bh = b * H_ + hh;
        if (which == 0) {
#pragma unroll
          for (int r = 0; r < 4; r++)
            q_ws[((size_t)bh * T_ + t + r) * HD_ + hdi] = (bf16)acc[mt][nt][r];
        } else if (which == 1) {
#pragma unroll
          for (int r = 0; r < 4; r++)
            k_ws[((size_t)bh * T_ + t + r) * HD_ + hdi] = (bf16)acc[mt][nt][r];
        } else {
          // v^T: 4 consecutive t -> one 8B store
          *(ushort4*)&vt_ws[((size_t)bh * HD_ + hdi) * T_ + t] =
              pack4(acc[mt][nt]);
        }
      }
    }
  } else {
#pragma unroll
    for (int nt = 0; nt < NF; nt++) {
      int col = n0 + bnb + nt * 16 + lx;
      float bias_f = bias[col];
#pragma unroll
      for (int mt = 0; mt < 4; mt++) {
        int mbase = m0 + amb + mt * 16 + quad * 4;
#pragma unroll
        for (int r = 0; r < 4; r++)
          Cout[(size_t)(mbase + r) * D_ + col] = acc[mt][nt][r] + bias_f;
      }
    }
  }
}

// ---------------------------------------------------------------------------
// Flash attention, double-buffered LDS with COUNTED vmcnt (T3/T4 minimum
// pipeline): stage tile t+1 into buf^1, s_waitcnt vmcnt(4) (never 0 in the
// main loop), raw s_barrier (no forced drain), compute tile t.  HBM/L2
// latency of t+1 hides under tile t's MFMA+softmax.  setprio(1) wraps the
// MFMA clusters (T5, +4-7% attn per m191).
// 1 block = 128 q of one (b,h); 4 waves x 32 q; kv-tile 64; grid 512.
// Output written in place into q_ws (block owns its 128 q rows).
// ---------------------------------------------------------------------------
__global__ __launch_bounds__(256, 2) void attn_kernel(
    bf16* __restrict__ q_ws, const bf16* __restrict__ k_ws,
    const bf16* __restrict__ vt_ws, const bf16* __restrict__ mem_k,
    const bf16* __restrict__ mem_vt) {
  __shared__ __align__(16) bf16 Kls[2 * 64 * 64];
  __shared__ __align__(16) bf16 Vls[2 * 64 * 64];
  char* KB = (char*)Kls;
  char* VB = (char*)Vls;
  const int tid = threadIdx.x;
  const int w = tid >> 6;
  const int lane = tid & 63;
  const int lx = lane & 15;
  const int quad = lane >> 4;
  const int bh = blockIdx.x & 31;      // XCD-locality
  const int qt = blockIdx.x >> 5;      // 16 q-tiles of 128
  const int q0 = qt * 128 + w * 32;
  const int h = bh & 15;

  const int srow1 = tid >> 3;              // 0..31
  const int sc1 = (tid & 7) ^ (srow1 & 7); // pre-swizzled source chunk
  // rows srow1+32 share (row&7) -> same swizzled chunk

  bf16* qbase = q_ws + ((size_t)bh * T_ + q0) * HD_;

  const bf16* kpl = k_ws + (size_t)bh * T_ * HD_;
  const bf16* vpl = vt_ws + (size_t)bh * HD_ * T_;
  const bf16* mkp = mem_k + (size_t)h * MEM_ * HD_;   // per-head plane
  const bf16* mvp = mem_vt + (size_t)h * HD_ * MEM_;

  // Stage kv-tile `it2` into LDS buffer `bi` (4 x gll16 per thread).
  auto stage = [&](int it2, int bi) {
    const int kv0 = it2 * 64;
    const bf16 *kp1, *kp2, *vp1, *vp2;
    if (kv0 < MEM_) {
      kp1 = mkp + (size_t)(kv0 + srow1) * HD_ + sc1 * 8;
      kp2 = kp1 + (size_t)32 * HD_;
      vp1 = mvp + (size_t)srow1 * MEM_ + kv0 + sc1 * 8;
      vp2 = vp1 + (size_t)32 * MEM_;
    } else {
      const int t0 = kv0 - MEM_;
      kp1 = kpl + (size_t)(t0 + srow1) * HD_ + sc1 * 8;
      kp2 = kp1 + (size_t)32 * HD_;
      vp1 = vpl + (size_t)srow1 * T_ + t0 + sc1 * 8;
      vp2 = vp1 + (size_t)32 * T_;
    }
    char* kb = KB + bi * 8192;
    char* vb = VB + bi * 8192;
    gll16(kp1, kb + tid * 16);
    gll16(kp2, kb + tid * 16 + 4096);
    gll16(vp1, vb + tid * 16);
    gll16(vp2, vb + tid * 16 + 4096);
  };

  // Q B-frags (k32); fold softmax scale AND log2(e) into Q:
  // s = (q*0.125*log2e) . k  ->  exp2(s) == exp(0.125 * q.k)
  const float QSCALE = 0.125f * 1.44269504089f;
  bf16x8 qf[2][2];
#pragma unroll
  for (int qg = 0; qg < 2; qg++)
#pragma unroll
    for (int hf = 0; hf < 2; hf++) {
      bf16x8 v = *(const bf16x8*)(qbase + (size_t)(qg * 16 + lx) * HD_ +
                                  hf * 32 + quad * 8);
#pragma unroll
      for (int i = 0; i < 8; i++)
        v[i] = (bf16)((float)v[i] * QSCALE);
      qf[qg][hf] = v;
    }

  f32x4 o[4][2];
#pragma unroll
  for (int mt = 0; mt < 4; mt++)
#pragma unroll
    for (int qg = 0; qg < 2; qg++) o[mt][qg] = (f32x4){0.f, 0.f, 0.f, 0.f};
  float lsum[2] = {0.f, 0.f};

  stage(0, 0);   // prologue prefetch

  for (int it = 0; it < NIT_; it++) {
    const int cur = it & 1;
    if (it + 1 < NIT_) {
      stage(it + 1, cur ^ 1);
      asm volatile("s_waitcnt vmcnt(4)" ::: "memory");   // cur's 4 loads done
    } else {
      asm volatile("s_waitcnt vmcnt(0)" ::: "memory");
    }
    __builtin_amdgcn_s_barrier();        // all waves' cur parts landed
    __builtin_amdgcn_sched_barrier(0);

    const char* KBc = KB + cur * 8192;
    const char* VBc = VB + cur * 8192;
    const int sw = (lx & 7) << 4;   // read-side swizzle (row&7 == lx&7)
    f32x4 s[4][2];
    __builtin_amdgcn_s_setprio(1);
#pragma unroll
    for (int g = 0; g < 4; g++) {
      const char* kb = KBc + (size_t)(g * 16 + lx) * 128;
      bf16x8 ka0 = *(const bf16x8*)(kb + ((quad * 16) ^ sw));
      bf16x8 ka1 = *(const bf16x8*)(kb + ((64 + quad * 16) ^ sw));
#pragma unroll
      for (int qg = 0; qg < 2; qg++) {
        s[g][qg] = (f32x4){0.f, 0.f, 0.f, 0.f};
        s[g][qg] = mfma16(ka0, qf[qg][0], s[g][qg]);
        s[g][qg] = mfma16(ka1, qf[qg][1], s[g][qg]);
      }
    }
    __builtin_amdgcn_s_setprio(0);

    s16x4 pb[2][4];
#pragma unroll
    for (int qg = 0; qg < 2; qg++) {
      float ps = 0.f;
#pragma unroll
      for (int g = 0; g < 4; g++) {
#pragma unroll
        for (int r = 0; r < 4; r++) {
          float p = __builtin_amdgcn_exp2f(s[g][qg][r]);  // raw v_exp_f32
          ps += p;
          pb[qg][g][r] = (short)bf16_bits(p);
        }
      }
      lsum[qg] += ps;
    }

    __builtin_amdgcn_s_setprio(1);
#pragma unroll
    for (int mt = 0; mt < 4; mt++) {
      const char* vb = VBc + (size_t)(mt * 16 + lx) * 128;
#pragma unroll
      for (int kk = 0; kk < 4; kk++) {
        s16x4 va = *(const s16x4*)(vb + ((kk * 32 + quad * 8) ^ sw));
#pragma unroll
        for (int qg = 0; qg < 2; qg++)
          o[mt][qg] = mfma16k16(va, pb[qg][kk], o[mt][qg]);
      }
    }
    __builtin_amdgcn_s_setprio(0);

    __builtin_amdgcn_sched_barrier(0);
    __builtin_amdgcn_s_barrier();   // all waves done reading buf[cur]
  }

  float inv[2];
#pragma unroll
  for (int qg = 0; qg < 2; qg++) {
    float s2 = lsum[qg];
    s2 += __shfl_xor(s2, 16);
    s2 += __shfl_xor(s2, 32);
    inv[qg] = 1.f / s2;
  }

#pragma unroll
  for (int qg = 0; qg < 2; qg++) {
#pragma unroll
    for (int mt = 0; mt < 4; mt++) {
      f32x4 ov;
#pragma unroll
      for (int r = 0; r < 4; r++) ov[r] = o[mt][qg][r] * inv[qg];
      *(ushort4*)(qbase + (size_t)(qg * 16 + lx) * HD_ + mt * 16 + quad * 4)
          = pack4(ov);
    }
  }
}

// ---------------------------------------------------------------------------
// Scratch plan (ws stays 26 MiB):
//   ws:    q_ws 0-8M | k_ws 8-16M | vt_ws 16-24M | mem_k 24-25M | mem_vt 25-26M
//   d_out: xb (bf16 x) 0-8M | wqb (bf16 w_qkv) 8-14M   [dead after gemm1;
//          gemm2 overwrites all of d_out with the real output]
//   wob (bf16 w_out) lands in k_ws space AFTER attn (k_ws dead by then).
// ---------------------------------------------------------------------------
extern "C" void kernel_launch(void* const* d_in, const int* in_sizes, int n_in,
                              void* d_out, int out_size, void* d_ws,
                              size_t ws_size, hipStream_t stream) {
  const float* x      = (const float*)d_in[0];   // [B,T,D]   f32
  const float* w_qkv  = (const float*)d_in[1];   // [3D,D]    f32
  const float* w_out  = (const float*)d_in[2];   // [D,D]     f32
  const float* b_out  = (const float*)d_in[3];   // [D]       f32
  const float* memory = (const float*)d_in[4];   // [MEM,D]   f32

  char* ws = (char*)d_ws;
  bf16* q_ws   = (bf16*)(ws);                    // [32][2048][64]  8 MiB
  bf16* k_ws   = (bf16*)(ws + (8u << 20));       // [32][2048][64]  8 MiB
  bf16* vt_ws  = (bf16*)(ws + (16u << 20));      // [32][64][2048]  8 MiB
  bf16* mem_k  = (bf16*)(ws + (24u << 20));      // [16][512][64]   1 MiB
  bf16* mem_vt = (bf16*)(ws + (25u << 20));      // [1024][512]     1 MiB
  float* out = (float*)d_out;                    // f32 per reference

  char* outc = (char*)d_out;
  bf16* xb  = (bf16*)(outc);                     // 8 MiB scratch in d_out
  bf16* wqb = (bf16*)(outc + (8u << 20));        // 6 MiB scratch in d_out
  bf16* wob = (bf16*)(ws + (8u << 20));          // reuses k_ws (dead post-attn)

  prep<<<dim3(3840), dim3(256), 0, stream>>>(x, w_qkv, memory,
                                             xb, wqb, mem_k, mem_vt);
  gemm_bt<0, false, 128><<<dim3(24, 32), dim3(256), 0, stream>>>(
      xb, wqb, nullptr, q_ws, k_ws, vt_ws, nullptr, 1024);
  attn_kernel<<<dim3(512), dim3(256), 0, stream>>>(
      q_ws, k_ws, vt_ws, mem_k, mem_vt);
  conv_bf16<<<dim3(512), dim3(256), 0, stream>>>(w_out, wob);
  gemm_bt<1, true, 64><<<dim3(16, 32), dim3(256), 0, stream>>>(
      q_ws, wob, b_out, nullptr, nullptr, nullptr, out, 1024);
}

// Round 3
// 201.639 us; speedup vs baseline: 1.1074x; 1.0552x over previous
//
#include <hip/hip_runtime.h>
#include <hip/hip_bf16.h>
#include <stdint.h>

// Problem constants
#define B_   2
#define T_   2048
#define D_   1024
#define H_   16
#define HD_  64
#define MEM_ 512
#define KV_  (MEM_ + T_)   // 2560
#define NIT_ (KV_ / 64)    // 40 kv-tiles of 64

using bf16 = __bf16;
typedef __bf16 bf16x8 __attribute__((ext_vector_type(8)));
typedef float  f32x4  __attribute__((ext_vector_type(4)));
typedef short  s16x4  __attribute__((ext_vector_type(4)));
typedef short  s16x8  __attribute__((ext_vector_type(8)));

__device__ __forceinline__ f32x4 mfma16(bf16x8 a, bf16x8 b, f32x4 c) {
  return __builtin_amdgcn_mfma_f32_16x16x32_bf16(a, b, c, 0, 0, 0);
}

// Async global->LDS, 16B per lane (dest = wave-uniform base + lane*16).
__device__ __forceinline__ void gll16(const void* g, void* l) {
  __builtin_amdgcn_global_load_lds(
      (const __attribute__((address_space(1))) unsigned int*)g,
      (__attribute__((address_space(3))) unsigned int*)l, 16, 0, 0);
}

__device__ __forceinline__ unsigned short bf16_bits(float f) {
  bf16 h = (bf16)f;
  return __builtin_bit_cast(unsigned short, h);
}

__device__ __forceinline__ ushort4 pack4(f32x4 v) {
  ushort4 p;
  p.x = bf16_bits(v[0]); p.y = bf16_bits(v[1]);
  p.z = bf16_bits(v[2]); p.w = bf16_bits(v[3]);
  return p;
}

__device__ __forceinline__ bf16x8 cvt8(f32x4 a, f32x4 b) {
  bf16x8 r;
  r[0] = (bf16)a[0]; r[1] = (bf16)a[1]; r[2] = (bf16)a[2]; r[3] = (bf16)a[3];
  r[4] = (bf16)b[0]; r[5] = (bf16)b[1]; r[6] = (bf16)b[2]; r[7] = (bf16)b[3];
  return r;
}

// ---------------------------------------------------------------------------
// prep (fused): blk 0-2047 x conv | 2048-3583 w_qkv conv | 3584-3839 fill_mem
//               | 3840-4351 w_out conv (only launched when ws has room).
// fill: memory [512][1024] f32 -> mem_k per-head plane [16][512][64] and
//       mem_vt [1024][512] (transposed).
// ---------------------------------------------------------------------------
__global__ void prep(const float* __restrict__ x, const float* __restrict__ wq,
                     const float* __restrict__ memory,
                     const float* __restrict__ wout,
                     bf16* __restrict__ xb, bf16* __restrict__ wqb,
                     bf16* __restrict__ mem_k, bf16* __restrict__ mem_vt,
                     bf16* __restrict__ wob) {
  int blk = blockIdx.x;
  if (blk < 3584) {
    const float* s = (blk < 2048) ? x : wq;
    bf16* d = (blk < 2048) ? xb : wqb;
    size_t i = ((size_t)(blk < 2048 ? blk : blk - 2048) * 256 + threadIdx.x) * 8;
    f32x4 a = *(const f32x4*)(s + i);
    f32x4 b = *(const f32x4*)(s + i + 4);
    *(bf16x8*)(d + i) = cvt8(a, b);
  } else if (blk < 3840) {
    int idx8 = ((blk - 3584) * 256 + threadIdx.x) * 8;   // [0, 512*1024)
    int m = idx8 >> 10, d0 = idx8 & 1023;
    int hh = d0 >> 6, hd0 = d0 & 63;
    f32x4 a = *(const f32x4*)(memory + idx8);
    f32x4 b = *(const f32x4*)(memory + idx8 + 4);
    bf16x8 r = cvt8(a, b);
    *(bf16x8*)&mem_k[((size_t)hh * MEM_ + m) * HD_ + hd0] = r;
#pragma unroll
    for (int j = 0; j < 8; j++)
      mem_vt[(size_t)(d0 + j) * MEM_ + m] = r[j];
  } else {
    size_t i = ((size_t)(blk - 3840) * 256 + threadIdx.x) * 8;
    f32x4 a = *(const f32x4*)(wout + i);
    f32x4 b = *(const f32x4*)(wout + i + 4);
    *(bf16x8*)(wob + i) = cvt8(a, b);
  }
}

// w_out conv fallback: runs AFTER attn (dest aliases k_ws, dead by then).
__global__ void conv_bf16(const float* __restrict__ s, bf16* __restrict__ d) {
  size_t i = ((size_t)blockIdx.x * 256 + threadIdx.x) * 8;
  f32x4 a = *(const f32x4*)(s + i);
  f32x4 b = *(const f32x4*)(s + i + 4);
  *(bf16x8*)(d + i) = cvt8(a, b);
}

// ---------------------------------------------------------------------------
// GEMM (B^T form): C[M,N] = A[M,K] * W[N,K]^T.  128 x NTILE tile, BK=64
// (32 MFMA per barrier pair), 4 waves (2x2).  Staging via global_load_lds w16
// into linear [rows][64] LDS; 16B-chunk XOR swizzle p = l ^ (row&7) applied
// on BOTH source chunk and ds_read (both-sides rule).
// EPI==0: scatter q/k -> [bh][t][64], v -> vt_ws[bh][hd][t] (transposed).
// EPI==1: bias add -> Cout [M][1024] f32.  APLANE: A is plane layout
//         [bh][t][64] (logical row m=b*T+t, col d=h*64+hd).
// ---------------------------------------------------------------------------
template <int EPI, bool APLANE, int NTILE>
__global__ __launch_bounds__(256, 3) void gemm_bt(
    const bf16* __restrict__ A, const bf16* __restrict__ W,
    const float* __restrict__ bias,
    bf16* __restrict__ q_ws, bf16* __restrict__ k_ws, bf16* __restrict__ vt_ws,
    float* __restrict__ Cout, int K) {
  constexpr int NF = NTILE / 32;        // n-frags per wave
  constexpr int NB = NTILE / 32;        // B-tile gll count
  __shared__ __align__(16) bf16 Als[128 * 64];
  __shared__ __align__(16) bf16 Bls[NTILE * 64];
  char* AB = (char*)Als;
  char* BB = (char*)Bls;
  const int m0 = blockIdx.y * 128;
  const int n0 = blockIdx.x * NTILE;
  const int tid = threadIdx.x;
  const int w = tid >> 6;
  const int lane = tid & 63;
  const int lx = lane & 15;
  const int quad = lane >> 4;
  const int amb = (w & 1) * 64;
  const int bnb = (w >> 1) * (NTILE / 2);
  const int srow = tid >> 3;                        // 0..31 (+32g per gll)
  const int cs = (tid & 7) ^ (srow & 7);            // swizzled source chunk

  f32x4 acc[4][NF];
#pragma unroll
  for (int i = 0; i < 4; i++)
#pragma unroll
    for (int j = 0; j < NF; j++) acc[i][j] = (f32x4){0.f, 0.f, 0.f, 0.f};

  for (int k0 = 0; k0 < K; k0 += 64) {
    const bf16* pa[4];
#pragma unroll
    for (int g = 0; g < 4; g++) {
      int r = srow + 32 * g;
      if constexpr (APLANE) {
        int hh = k0 >> 6, hd = cs * 8;
        int mA = m0 + r;
        pa[g] = A + ((size_t)((mA >> 11) * H_ + hh) * T_ + (mA & 2047)) * HD_ + hd;
      } else {
        pa[g] = A + (size_t)(m0 + r) * K + k0 + cs * 8;
      }
    }
    const bf16* pb[NB];
#pragma unroll
    for (int g = 0; g < NB; g++)
      pb[g] = W + (size_t)(n0 + srow + 32 * g) * K + k0 + cs * 8;

    __syncthreads();   // prev iteration's LDS reads done
#pragma unroll
    for (int g = 0; g < 4; g++) gll16(pa[g], AB + g * 4096 + tid * 16);
#pragma unroll
    for (int g = 0; g < NB; g++) gll16(pb[g], BB + g * 4096 + tid * 16);
    __syncthreads();   // drains vmcnt -> tiles valid

    bf16x8 af[4][2], bfr[NF][2];
    const int rk = (lx & 7) << 4;   // read-side swizzle key (row&7 == lx&7)
#pragma unroll
    for (int mt = 0; mt < 4; mt++)
#pragma unroll
      for (int kh = 0; kh < 2; kh++)
        af[mt][kh] = *(const bf16x8*)(AB + (size_t)(amb + mt * 16 + lx) * 128 +
                                      ((quad * 16 + kh * 64) ^ rk));
#pragma unroll
    for (int nt = 0; nt < NF; nt++)
#pragma unroll
      for (int kh = 0; kh < 2; kh++)
        bfr[nt][kh] = *(const bf16x8*)(BB + (size_t)(bnb + nt * 16 + lx) * 128 +
                                       ((quad * 16 + kh * 64) ^ rk));
#pragma unroll
    for (int kh = 0; kh < 2; kh++)
#pragma unroll
      for (int mt = 0; mt < 4; mt++)
#pragma unroll
        for (int nt = 0; nt < NF; nt++)
          acc[mt][nt] = mfma16(af[mt][kh], bfr[nt][kh], acc[mt][nt]);
  }

  // Epilogue. C/D layout: row = quad*4+reg (m), col = lane&15 (n).
  if (EPI == 0) {
#pragma unroll
    for (int mt = 0; mt < 4; mt++) {
      int mbase = m0 + amb + mt * 16 + quad * 4;
      int b = mbase >> 11;        // T=2048
      int t = mbase & 2047;
#pragma unroll
      for (int nt = 0; nt < NF; nt++) {
        int col = n0 + bnb + nt * 16 + lx;     // [0,3072)
        int which = col >> 10;                 // 0=q 1=k 2=v
        int d = col & 1023;
        int hh = d >> 6, hdi = d & 63;
        int bh = b * H_ + hh;
        if (which == 0) {
#pragma unroll
          for (int r = 0; r < 4; r++)
            q_ws[((size_t)bh * T_ + t + r) * HD_ + hdi] = (bf16)acc[mt][nt][r];
        } else if (which == 1) {
#pragma unroll
          for (int r = 0; r < 4; r++)
            k_ws[((size_t)bh * T_ + t + r) * HD_ + hdi] = (bf16)acc[mt][nt][r];
        } else {
          // v^T: 4 consecutive t -> one 8B store
          *(ushort4*)&vt_ws[((size_t)bh * HD_ + hdi) * T_ + t] =
              pack4(acc[mt][nt]);
        }
      }
    }
  } else {
#pragma unroll
    for (int nt = 0; nt < NF; nt++) {
      int col = n0 + bnb + nt * 16 + lx;
      float bias_f = bias[col];
#pragma unroll
      for (int mt = 0; mt < 4; mt++) {
        int mbase = m0 + amb + mt * 16 + quad * 4;
#pragma unroll
        for (int r = 0; r < 4; r++)
          Cout[(size_t)(mbase + r) * D_ + col] = acc[mt][nt][r] + bias_f;
      }
    }
  }
}

// ---------------------------------------------------------------------------
// Flash attention, double-buffered LDS + counted vmcnt, PV at FULL-RATE k32.
//
// PV k32 trick: MFMA's k is an arbitrary contraction label.  Relabel logical
// k = quad*8+i  ->  actual kv = 16*(i>=4) + quad*4 + (i&3)  (bijective over
// the 32-kv pair-block).  Then the B-frag is just concat(pb[2p], pb[2p+1])
// (registers, no shuffles) and the A-frag is the concat of the SAME two 8B
// V reads the k16 version already did.  16 k32 MFMAs replace 32 k16 MFMAs:
// PV MFMA-pipe time halves (26 -> ~19.4 us total MFMA busy-time).
//
// 1 block = 128 q of one (b,h); 4 waves x 32 q; kv-tile 64; grid 512.
// Output written in place into q_ws (block owns its 128 q rows).
// ---------------------------------------------------------------------------
__global__ __launch_bounds__(256, 2) void attn_kernel(
    bf16* __restrict__ q_ws, const bf16* __restrict__ k_ws,
    const bf16* __restrict__ vt_ws, const bf16* __restrict__ mem_k,
    const bf16* __restrict__ mem_vt) {
  __shared__ __align__(16) bf16 Kls[2 * 64 * 64];
  __shared__ __align__(16) bf16 Vls[2 * 64 * 64];
  char* KB = (char*)Kls;
  char* VB = (char*)Vls;
  const int tid = threadIdx.x;
  const int w = tid >> 6;
  const int lane = tid & 63;
  const int lx = lane & 15;
  const int quad = lane >> 4;
  const int bh = blockIdx.x & 31;      // XCD-locality
  const int qt = blockIdx.x >> 5;      // 16 q-tiles of 128
  const int q0 = qt * 128 + w * 32;
  const int h = bh & 15;

  const int srow1 = tid >> 3;              // 0..31
  const int sc1 = (tid & 7) ^ (srow1 & 7); // pre-swizzled source chunk
  // rows srow1+32 share (row&7) -> same swizzled chunk

  bf16* qbase = q_ws + ((size_t)bh * T_ + q0) * HD_;

  const bf16* kpl = k_ws + (size_t)bh * T_ * HD_;
  const bf16* vpl = vt_ws + (size_t)bh * HD_ * T_;
  const bf16* mkp = mem_k + (size_t)h * MEM_ * HD_;   // per-head plane
  const bf16* mvp = mem_vt + (size_t)h * HD_ * MEM_;

  // Stage kv-tile `it2` into LDS buffer `bi` (4 x gll16 per thread).
  auto stage = [&](int it2, int bi) {
    const int kv0 = it2 * 64;
    const bf16 *kp1, *kp2, *vp1, *vp2;
    if (kv0 < MEM_) {
      kp1 = mkp + (size_t)(kv0 + srow1) * HD_ + sc1 * 8;
      kp2 = kp1 + (size_t)32 * HD_;
      vp1 = mvp + (size_t)srow1 * MEM_ + kv0 + sc1 * 8;
      vp2 = vp1 + (size_t)32 * MEM_;
    } else {
      const int t0 = kv0 - MEM_;
      kp1 = kpl + (size_t)(t0 + srow1) * HD_ + sc1 * 8;
      kp2 = kp1 + (size_t)32 * HD_;
      vp1 = vpl + (size_t)srow1 * T_ + t0 + sc1 * 8;
      vp2 = vp1 + (size_t)32 * T_;
    }
    char* kb = KB + bi * 8192;
    char* vb = VB + bi * 8192;
    gll16(kp1, kb + tid * 16);
    gll16(kp2, kb + tid * 16 + 4096);
    gll16(vp1, vb + tid * 16);
    gll16(vp2, vb + tid * 16 + 4096);
  };

  // Q B-frags (k32); fold softmax scale AND log2(e) into Q:
  // s = (q*0.125*log2e) . k  ->  exp2(s) == exp(0.125 * q.k)
  const float QSCALE = 0.125f * 1.44269504089f;
  bf16x8 qf[2][2];
#pragma unroll
  for (int qg = 0; qg < 2; qg++)
#pragma unroll
    for (int hf = 0; hf < 2; hf++) {
      bf16x8 v = *(const bf16x8*)(qbase + (size_t)(qg * 16 + lx) * HD_ +
                                  hf * 32 + quad * 8);
#pragma unroll
      for (int i = 0; i < 8; i++)
        v[i] = (bf16)((float)v[i] * QSCALE);
      qf[qg][hf] = v;
    }

  f32x4 o[4][2];
#pragma unroll
  for (int mt = 0; mt < 4; mt++)
#pragma unroll
    for (int qg = 0; qg < 2; qg++) o[mt][qg] = (f32x4){0.f, 0.f, 0.f, 0.f};
  float lsum[2] = {0.f, 0.f};

  stage(0, 0);   // prologue prefetch

  for (int it = 0; it < NIT_; it++) {
    const int cur = it & 1;
    if (it + 1 < NIT_) {
      stage(it + 1, cur ^ 1);
      asm volatile("s_waitcnt vmcnt(4)" ::: "memory");   // cur's 4 loads done
    } else {
      asm volatile("s_waitcnt vmcnt(0)" ::: "memory");
    }
    __builtin_amdgcn_s_barrier();        // all waves' cur parts landed
    __builtin_amdgcn_sched_barrier(0);

    const char* KBc = KB + cur * 8192;
    const char* VBc = VB + cur * 8192;
    const int sw = (lx & 7) << 4;   // read-side swizzle (row&7 == lx&7)
    f32x4 s[4][2];
    __builtin_amdgcn_s_setprio(1);
#pragma unroll
    for (int g = 0; g < 4; g++) {
      const char* kb = KBc + (size_t)(g * 16 + lx) * 128;
      bf16x8 ka0 = *(const bf16x8*)(kb + ((quad * 16) ^ sw));
      bf16x8 ka1 = *(const bf16x8*)(kb + ((64 + quad * 16) ^ sw));
#pragma unroll
      for (int qg = 0; qg < 2; qg++) {
        s[g][qg] = (f32x4){0.f, 0.f, 0.f, 0.f};
        s[g][qg] = mfma16(ka0, qf[qg][0], s[g][qg]);
        s[g][qg] = mfma16(ka1, qf[qg][1], s[g][qg]);
      }
    }
    __builtin_amdgcn_s_setprio(0);

    // softmax: p = exp2(s); pack straight into the k32 B-frag halves.
    s16x8 pk[2][2];   // [qg][pair]: elems 0-3 = group 2p, 4-7 = group 2p+1
#pragma unroll
    for (int qg = 0; qg < 2; qg++) {
      float ps = 0.f;
#pragma unroll
      for (int g = 0; g < 4; g++) {
#pragma unroll
        for (int r = 0; r < 4; r++) {
          float p = __builtin_amdgcn_exp2f(s[g][qg][r]);  // raw v_exp_f32
          ps += p;
          pk[qg][g >> 1][(g & 1) * 4 + r] = (short)bf16_bits(p);
        }
      }
      lsum[qg] += ps;
    }

    __builtin_amdgcn_s_setprio(1);
#pragma unroll
    for (int mt = 0; mt < 4; mt++) {
      const char* vb = VBc + (size_t)(mt * 16 + lx) * 128;
#pragma unroll
      for (int p = 0; p < 2; p++) {
        // A-frag: V[d][kv] at kv-chunks p*32+quad*4 and p*32+16+quad*4
        s16x4 lo = *(const s16x4*)(vb + ((p * 64 + quad * 8) ^ sw));
        s16x4 hi = *(const s16x4*)(vb + ((p * 64 + 32 + quad * 8) ^ sw));
        s16x8 cat = __builtin_shufflevector(lo, hi, 0, 1, 2, 3, 4, 5, 6, 7);
        bf16x8 va = __builtin_bit_cast(bf16x8, cat);
#pragma unroll
        for (int qg = 0; qg < 2; qg++)
          o[mt][qg] = mfma16(va, __builtin_bit_cast(bf16x8, pk[qg][p]),
                             o[mt][qg]);
      }
    }
    __builtin_amdgcn_s_setprio(0);

    __builtin_amdgcn_sched_barrier(0);
    __builtin_amdgcn_s_barrier();   // all waves done reading buf[cur]
  }

  float inv[2];
#pragma unroll
  for (int qg = 0; qg < 2; qg++) {
    float s2 = lsum[qg];
    s2 += __shfl_xor(s2, 16);
    s2 += __shfl_xor(s2, 32);
    inv[qg] = 1.f / s2;
  }

#pragma unroll
  for (int qg = 0; qg < 2; qg++) {
#pragma unroll
    for (int mt = 0; mt < 4; mt++) {
      f32x4 ov;
#pragma unroll
      for (int r = 0; r < 4; r++) ov[r] = o[mt][qg][r] * inv[qg];
      *(ushort4*)(qbase + (size_t)(qg * 16 + lx) * HD_ + mt * 16 + quad * 4)
          = pack4(ov);
    }
  }
}

// ---------------------------------------------------------------------------
// Scratch plan:
//   ws:    q_ws 0-8M | k_ws 8-16M | vt_ws 16-24M | mem_k 24-25M | mem_vt 25-26M
//          | wob 26-28M (only if ws_size >= 28M; else wob aliases k_ws and is
//          converted AFTER attn by the fallback conv kernel)
//   d_out: xb (bf16 x) 0-8M | wqb (bf16 w_qkv) 8-14M   [dead after gemm1;
//          gemm2 overwrites all of d_out with the real output]
// ---------------------------------------------------------------------------
extern "C" void kernel_launch(void* const* d_in, const int* in_sizes, int n_in,
                              void* d_out, int out_size, void* d_ws,
                              size_t ws_size, hipStream_t stream) {
  const float* x      = (const float*)d_in[0];   // [B,T,D]   f32
  const float* w_qkv  = (const float*)d_in[1];   // [3D,D]    f32
  const float* w_out  = (const float*)d_in[2];   // [D,D]     f32
  const float* b_out  = (const float*)d_in[3];   // [D]       f32
  const float* memory = (const float*)d_in[4];   // [MEM,D]   f32

  char* ws = (char*)d_ws;
  bf16* q_ws   = (bf16*)(ws);                    // [32][2048][64]  8 MiB
  bf16* k_ws   = (bf16*)(ws + (8u << 20));       // [32][2048][64]  8 MiB
  bf16* vt_ws  = (bf16*)(ws + (16u << 20));      // [32][64][2048]  8 MiB
  bf16* mem_k  = (bf16*)(ws + (24u << 20));      // [16][512][64]   1 MiB
  bf16* mem_vt = (bf16*)(ws + (25u << 20));      // [1024][512]     1 MiB
  float* out = (float*)d_out;                    // f32 per reference

  char* outc = (char*)d_out;
  bf16* xb  = (bf16*)(outc);                     // 8 MiB scratch in d_out
  bf16* wqb = (bf16*)(outc + (8u << 20));        // 6 MiB scratch in d_out

  const bool big_ws = ws_size >= (28u << 20);
  bf16* wob = big_ws ? (bf16*)(ws + (26u << 20))   // private 2 MiB
                     : (bf16*)(ws + (8u << 20));   // aliases k_ws (post-attn)

  prep<<<dim3(big_ws ? 4352 : 3840), dim3(256), 0, stream>>>(
      x, w_qkv, memory, w_out, xb, wqb, mem_k, mem_vt, wob);
  gemm_bt<0, false, 128><<<dim3(24, 32), dim3(256), 0, stream>>>(
      xb, wqb, nullptr, q_ws, k_ws, vt_ws, nullptr, 1024);
  attn_kernel<<<dim3(512), dim3(256), 0, stream>>>(
      q_ws, k_ws, vt_ws, mem_k, mem_vt);
  if (!big_ws)
    conv_bf16<<<dim3(512), dim3(256), 0, stream>>>(w_out, wob);
  gemm_bt<1, true, 64><<<dim3(16, 32), dim3(256), 0, stream>>>(
      q_ws, wob, b_out, nullptr, nullptr, nullptr, out, 1024);
}

// Round 4
// 192.184 us; speedup vs baseline: 1.1619x; 1.0492x over previous
//
#include <hip/hip_runtime.h>
#include <hip/hip_bf16.h>
#include <stdint.h>

// Problem constants
#define B_   2
#define T_   2048
#define D_   1024
#define H_   16
#define HD_  64
#define MEM_ 512
#define KV_  (MEM_ + T_)   // 2560
#define NIT_ (KV_ / 64)    // 40 kv-tiles of 64

using bf16 = __bf16;
typedef __bf16 bf16x8 __attribute__((ext_vector_type(8)));
typedef float  f32x4  __attribute__((ext_vector_type(4)));
typedef short  s16x4  __attribute__((ext_vector_type(4)));
typedef short  s16x8  __attribute__((ext_vector_type(8)));

__device__ __forceinline__ f32x4 mfma16(bf16x8 a, bf16x8 b, f32x4 c) {
  return __builtin_amdgcn_mfma_f32_16x16x32_bf16(a, b, c, 0, 0, 0);
}

// Async global->LDS, 16B per lane (dest = wave-uniform base + lane*16).
__device__ __forceinline__ void gll16(const void* g, void* l) {
  __builtin_amdgcn_global_load_lds(
      (const __attribute__((address_space(1))) unsigned int*)g,
      (__attribute__((address_space(3))) unsigned int*)l, 16, 0, 0);
}

__device__ __forceinline__ unsigned short bf16_bits(float f) {
  bf16 h = (bf16)f;
  return __builtin_bit_cast(unsigned short, h);
}

__device__ __forceinline__ ushort4 pack4(f32x4 v) {
  ushort4 p;
  p.x = bf16_bits(v[0]); p.y = bf16_bits(v[1]);
  p.z = bf16_bits(v[2]); p.w = bf16_bits(v[3]);
  return p;
}

__device__ __forceinline__ bf16x8 cvt8(f32x4 a, f32x4 b) {
  bf16x8 r;
  r[0] = (bf16)a[0]; r[1] = (bf16)a[1]; r[2] = (bf16)a[2]; r[3] = (bf16)a[3];
  r[4] = (bf16)b[0]; r[5] = (bf16)b[1]; r[6] = (bf16)b[2]; r[7] = (bf16)b[3];
  return r;
}

// ---------------------------------------------------------------------------
// prep (fused): blk 0-2047 x conv | 2048-3583 w_qkv conv | 3584-3839 fill_mem
//               | 3840-4351 w_out conv (only launched when ws has room).
// fill: memory [512][1024] f32 -> mem_k per-head plane [16][512][64] and
//       mem_vt [1024][512] (transposed).
// ---------------------------------------------------------------------------
__global__ void prep(const float* __restrict__ x, const float* __restrict__ wq,
                     const float* __restrict__ memory,
                     const float* __restrict__ wout,
                     bf16* __restrict__ xb, bf16* __restrict__ wqb,
                     bf16* __restrict__ mem_k, bf16* __restrict__ mem_vt,
                     bf16* __restrict__ wob) {
  int blk = blockIdx.x;
  if (blk < 3584) {
    const float* s = (blk < 2048) ? x : wq;
    bf16* d = (blk < 2048) ? xb : wqb;
    size_t i = ((size_t)(blk < 2048 ? blk : blk - 2048) * 256 + threadIdx.x) * 8;
    f32x4 a = *(const f32x4*)(s + i);
    f32x4 b = *(const f32x4*)(s + i + 4);
    *(bf16x8*)(d + i) = cvt8(a, b);
  } else if (blk < 3840) {
    int idx8 = ((blk - 3584) * 256 + threadIdx.x) * 8;   // [0, 512*1024)
    int m = idx8 >> 10, d0 = idx8 & 1023;
    int hh = d0 >> 6, hd0 = d0 & 63;
    f32x4 a = *(const f32x4*)(memory + idx8);
    f32x4 b = *(const f32x4*)(memory + idx8 + 4);
    bf16x8 r = cvt8(a, b);
    *(bf16x8*)&mem_k[((size_t)hh * MEM_ + m) * HD_ + hd0] = r;
#pragma unroll
    for (int j = 0; j < 8; j++)
      mem_vt[(size_t)(d0 + j) * MEM_ + m] = r[j];
  } else {
    size_t i = ((size_t)(blk - 3840) * 256 + threadIdx.x) * 8;
    f32x4 a = *(const f32x4*)(wout + i);
    f32x4 b = *(const f32x4*)(wout + i + 4);
    *(bf16x8*)(wob + i) = cvt8(a, b);
  }
}

// w_out conv fallback: runs AFTER attn (dest aliases k_ws, dead by then).
__global__ void conv_bf16(const float* __restrict__ s, bf16* __restrict__ d) {
  size_t i = ((size_t)blockIdx.x * 256 + threadIdx.x) * 8;
  f32x4 a = *(const f32x4*)(s + i);
  f32x4 b = *(const f32x4*)(s + i + 4);
  *(bf16x8*)(d + i) = cvt8(a, b);
}

// ---------------------------------------------------------------------------
// GEMM (B^T form): C[M,N] = A[M,K] * W[N,K]^T.  128 x NTILE tile, BK=64
// (32 MFMA per barrier pair), 4 waves (2x2).  Staging via global_load_lds w16
// into linear [rows][64] LDS; 16B-chunk XOR swizzle p = l ^ (row&7) applied
// on BOTH source chunk and ds_read (both-sides rule).
// EPI==0: scatter q/k -> [bh][t][64], v -> vt_ws[bh][hd][t] (transposed).
// EPI==1: bias add -> Cout [M][1024] f32.  APLANE: A is plane layout
//         [bh][t][64] (logical row m=b*T+t, col d=h*64+hd).
// ---------------------------------------------------------------------------
template <int EPI, bool APLANE, int NTILE>
__global__ __launch_bounds__(256, 3) void gemm_bt(
    const bf16* __restrict__ A, const bf16* __restrict__ W,
    const float* __restrict__ bias,
    bf16* __restrict__ q_ws, bf16* __restrict__ k_ws, bf16* __restrict__ vt_ws,
    float* __restrict__ Cout, int K) {
  constexpr int NF = NTILE / 32;        // n-frags per wave
  constexpr int NB = NTILE / 32;        // B-tile gll count
  __shared__ __align__(16) bf16 Als[128 * 64];
  __shared__ __align__(16) bf16 Bls[NTILE * 64];
  char* AB = (char*)Als;
  char* BB = (char*)Bls;
  const int m0 = blockIdx.y * 128;
  const int n0 = blockIdx.x * NTILE;
  const int tid = threadIdx.x;
  const int w = tid >> 6;
  const int lane = tid & 63;
  const int lx = lane & 15;
  const int quad = lane >> 4;
  const int amb = (w & 1) * 64;
  const int bnb = (w >> 1) * (NTILE / 2);
  const int srow = tid >> 3;                        // 0..31 (+32g per gll)
  const int cs = (tid & 7) ^ (srow & 7);            // swizzled source chunk

  f32x4 acc[4][NF];
#pragma unroll
  for (int i = 0; i < 4; i++)
#pragma unroll
    for (int j = 0; j < NF; j++) acc[i][j] = (f32x4){0.f, 0.f, 0.f, 0.f};

  for (int k0 = 0; k0 < K; k0 += 64) {
    const bf16* pa[4];
#pragma unroll
    for (int g = 0; g < 4; g++) {
      int r = srow + 32 * g;
      if constexpr (APLANE) {
        int hh = k0 >> 6, hd = cs * 8;
        int mA = m0 + r;
        pa[g] = A + ((size_t)((mA >> 11) * H_ + hh) * T_ + (mA & 2047)) * HD_ + hd;
      } else {
        pa[g] = A + (size_t)(m0 + r) * K + k0 + cs * 8;
      }
    }
    const bf16* pb[NB];
#pragma unroll
    for (int g = 0; g < NB; g++)
      pb[g] = W + (size_t)(n0 + srow + 32 * g) * K + k0 + cs * 8;

    __syncthreads();   // prev iteration's LDS reads done
#pragma unroll
    for (int g = 0; g < 4; g++) gll16(pa[g], AB + g * 4096 + tid * 16);
#pragma unroll
    for (int g = 0; g < NB; g++) gll16(pb[g], BB + g * 4096 + tid * 16);
    __syncthreads();   // drains vmcnt -> tiles valid

    bf16x8 af[4][2], bfr[NF][2];
    const int rk = (lx & 7) << 4;   // read-side swizzle key (row&7 == lx&7)
#pragma unroll
    for (int mt = 0; mt < 4; mt++)
#pragma unroll
      for (int kh = 0; kh < 2; kh++)
        af[mt][kh] = *(const bf16x8*)(AB + (size_t)(amb + mt * 16 + lx) * 128 +
                                      ((quad * 16 + kh * 64) ^ rk));
#pragma unroll
    for (int nt = 0; nt < NF; nt++)
#pragma unroll
      for (int kh = 0; kh < 2; kh++)
        bfr[nt][kh] = *(const bf16x8*)(BB + (size_t)(bnb + nt * 16 + lx) * 128 +
                                       ((quad * 16 + kh * 64) ^ rk));
#pragma unroll
    for (int kh = 0; kh < 2; kh++)
#pragma unroll
      for (int mt = 0; mt < 4; mt++)
#pragma unroll
        for (int nt = 0; nt < NF; nt++)
          acc[mt][nt] = mfma16(af[mt][kh], bfr[nt][kh], acc[mt][nt]);
  }

  // Epilogue. C/D layout: row = quad*4+reg (m), col = lane&15 (n).
  if (EPI == 0) {
#pragma unroll
    for (int mt = 0; mt < 4; mt++) {
      int mbase = m0 + amb + mt * 16 + quad * 4;
      int b = mbase >> 11;        // T=2048
      int t = mbase & 2047;
#pragma unroll
      for (int nt = 0; nt < NF; nt++) {
        int col = n0 + bnb + nt * 16 + lx;     // [0,3072)
        int which = col >> 10;                 // 0=q 1=k 2=v
        int d = col & 1023;
        int hh = d >> 6, hdi = d & 63;
        int bh = b * H_ + hh;
        if (which == 0) {
#pragma unroll
          for (int r = 0; r < 4; r++)
            q_ws[((size_t)bh * T_ + t + r) * HD_ + hdi] = (bf16)acc[mt][nt][r];
        } else if (which == 1) {
#pragma unroll
          for (int r = 0; r < 4; r++)
            k_ws[((size_t)bh * T_ + t + r) * HD_ + hdi] = (bf16)acc[mt][nt][r];
        } else {
          // v^T: 4 consecutive t -> one 8B store
          *(ushort4*)&vt_ws[((size_t)bh * HD_ + hdi) * T_ + t] =
              pack4(acc[mt][nt]);
        }
      }
    }
  } else {
#pragma unroll
    for (int nt = 0; nt < NF; nt++) {
      int col = n0 + bnb + nt * 16 + lx;
      float bias_f = bias[col];
#pragma unroll
      for (int mt = 0; mt < 4; mt++) {
        int mbase = m0 + amb + mt * 16 + quad * 4;
#pragma unroll
        for (int r = 0; r < 4; r++)
          Cout[(size_t)(mbase + r) * D_ + col] = acc[mt][nt][r] + bias_f;
      }
    }
  }
}

// ---------------------------------------------------------------------------
// Flash attention, 8-wave (512-thread) blocks: 2 blocks/CU x 8 waves =
// 16 waves/CU (4/SIMD, 50% occupancy) vs the old 4-wave 25%.  Each wave owns
// 16 q rows (the qg loop collapsed); staging per block is UNCHANGED (64x64
// K/V tiles, now exactly 1 gll16/thread/buffer -> counted wait vmcnt(2)).
// Double-buffered LDS + counted vmcnt + raw s_barrier; PV at full-rate k32
// via the contraction-relabel trick (see R3).
// 1 block = 128 q of one (b,h); kv-tile 64; grid 512; output in q_ws.
// ---------------------------------------------------------------------------
__global__ __launch_bounds__(512, 4) void attn_kernel(
    bf16* __restrict__ q_ws, const bf16* __restrict__ k_ws,
    const bf16* __restrict__ vt_ws, const bf16* __restrict__ mem_k,
    const bf16* __restrict__ mem_vt) {
  __shared__ __align__(16) bf16 Kls[2 * 64 * 64];
  __shared__ __align__(16) bf16 Vls[2 * 64 * 64];
  char* KB = (char*)Kls;
  char* VB = (char*)Vls;
  const int tid = threadIdx.x;
  const int w = tid >> 6;              // 8 waves
  const int lane = tid & 63;
  const int lx = lane & 15;
  const int quad = lane >> 4;
  const int bh = blockIdx.x & 31;      // XCD-locality
  const int qt = blockIdx.x >> 5;      // 16 q-tiles of 128
  const int q0 = qt * 128 + w * 16;    // 16 q rows per wave
  const int h = bh & 15;

  const int srow = tid >> 3;               // 0..63 (full tile, 1 gll/buffer)
  const int sc = (tid & 7) ^ (srow & 7);   // pre-swizzled source chunk

  bf16* qbase = q_ws + ((size_t)bh * T_ + q0) * HD_;

  const bf16* kpl = k_ws + (size_t)bh * T_ * HD_;
  const bf16* vpl = vt_ws + (size_t)bh * HD_ * T_;
  const bf16* mkp = mem_k + (size_t)h * MEM_ * HD_;   // per-head plane
  const bf16* mvp = mem_vt + (size_t)h * HD_ * MEM_;

  // Stage kv-tile `it2` into LDS buffer `bi` (2 x gll16 per thread).
  auto stage = [&](int it2, int bi) {
    const int kv0 = it2 * 64;
    const bf16 *kp, *vp;
    if (kv0 < MEM_) {
      kp = mkp + (size_t)(kv0 + srow) * HD_ + sc * 8;
      vp = mvp + (size_t)srow * MEM_ + kv0 + sc * 8;
    } else {
      const int t0 = kv0 - MEM_;
      kp = kpl + (size_t)(t0 + srow) * HD_ + sc * 8;
      vp = vpl + (size_t)srow * T_ + t0 + sc * 8;
    }
    gll16(kp, KB + bi * 8192 + tid * 16);
    gll16(vp, VB + bi * 8192 + tid * 16);
  };

  // Q B-frag (k32); fold softmax scale AND log2(e) into Q:
  // s = (q*0.125*log2e) . k  ->  exp2(s) == exp(0.125 * q.k)
  const float QSCALE = 0.125f * 1.44269504089f;
  bf16x8 qf[2];
#pragma unroll
  for (int hf = 0; hf < 2; hf++) {
    bf16x8 v = *(const bf16x8*)(qbase + (size_t)lx * HD_ + hf * 32 + quad * 8);
#pragma unroll
    for (int i = 0; i < 8; i++)
      v[i] = (bf16)((float)v[i] * QSCALE);
    qf[hf] = v;
  }

  f32x4 o[4];
#pragma unroll
  for (int mt = 0; mt < 4; mt++) o[mt] = (f32x4){0.f, 0.f, 0.f, 0.f};
  float lsum = 0.f;

  stage(0, 0);   // prologue prefetch (2 loads outstanding)

  for (int it = 0; it < NIT_; it++) {
    const int cur = it & 1;
    if (it + 1 < NIT_) {
      stage(it + 1, cur ^ 1);
      asm volatile("s_waitcnt vmcnt(2)" ::: "memory");   // cur's 2 loads done
    } else {
      asm volatile("s_waitcnt vmcnt(0)" ::: "memory");
    }
    __builtin_amdgcn_s_barrier();        // all waves' cur parts landed
    __builtin_amdgcn_sched_barrier(0);

    const char* KBc = KB + cur * 8192;
    const char* VBc = VB + cur * 8192;
    const int sw = (lx & 7) << 4;   // read-side swizzle (row&7 == lx&7)
    f32x4 s[4];
    __builtin_amdgcn_s_setprio(1);
#pragma unroll
    for (int g = 0; g < 4; g++) {
      const char* kb = KBc + (size_t)(g * 16 + lx) * 128;
      bf16x8 ka0 = *(const bf16x8*)(kb + ((quad * 16) ^ sw));
      bf16x8 ka1 = *(const bf16x8*)(kb + ((64 + quad * 16) ^ sw));
      s[g] = (f32x4){0.f, 0.f, 0.f, 0.f};
      s[g] = mfma16(ka0, qf[0], s[g]);
      s[g] = mfma16(ka1, qf[1], s[g]);
    }
    __builtin_amdgcn_s_setprio(0);

    // softmax: p = exp2(s); pack straight into the k32 B-frag halves.
    s16x8 pk[2];   // [pair]: elems 0-3 = group 2p, 4-7 = group 2p+1
    {
      float ps = 0.f;
#pragma unroll
      for (int g = 0; g < 4; g++) {
#pragma unroll
        for (int r = 0; r < 4; r++) {
          float p = __builtin_amdgcn_exp2f(s[g][r]);  // raw v_exp_f32
          ps += p;
          pk[g >> 1][(g & 1) * 4 + r] = (short)bf16_bits(p);
        }
      }
      lsum += ps;
    }

    __builtin_amdgcn_s_setprio(1);
#pragma unroll
    for (int mt = 0; mt < 4; mt++) {
      const char* vb = VBc + (size_t)(mt * 16 + lx) * 128;
#pragma unroll
      for (int p = 0; p < 2; p++) {
        // A-frag: V[d][kv] at kv-chunks p*32+quad*4 and p*32+16+quad*4
        s16x4 lo = *(const s16x4*)(vb + ((p * 64 + quad * 8) ^ sw));
        s16x4 hi = *(const s16x4*)(vb + ((p * 64 + 32 + quad * 8) ^ sw));
        s16x8 cat = __builtin_shufflevector(lo, hi, 0, 1, 2, 3, 4, 5, 6, 7);
        bf16x8 va = __builtin_bit_cast(bf16x8, cat);
        o[mt] = mfma16(va, __builtin_bit_cast(bf16x8, pk[p]), o[mt]);
      }
    }
    __builtin_amdgcn_s_setprio(0);

    __builtin_amdgcn_sched_barrier(0);
    __builtin_amdgcn_s_barrier();   // all waves done reading buf[cur]
  }

  float s2 = lsum;
  s2 += __shfl_xor(s2, 16);
  s2 += __shfl_xor(s2, 32);
  float inv = 1.f / s2;

#pragma unroll
  for (int mt = 0; mt < 4; mt++) {
    f32x4 ov;
#pragma unroll
    for (int r = 0; r < 4; r++) ov[r] = o[mt][r] * inv;
    *(ushort4*)(qbase + (size_t)lx * HD_ + mt * 16 + quad * 4) = pack4(ov);
  }
}

// ---------------------------------------------------------------------------
// Scratch plan:
//   ws:    q_ws 0-8M | k_ws 8-16M | vt_ws 16-24M | mem_k 24-25M | mem_vt 25-26M
//          | wob 26-28M (only if ws_size >= 28M; else wob aliases k_ws and is
//          converted AFTER attn by the fallback conv kernel)
//   d_out: xb (bf16 x) 0-8M | wqb (bf16 w_qkv) 8-14M   [dead after gemm1;
//          gemm2 overwrites all of d_out with the real output]
// ---------------------------------------------------------------------------
extern "C" void kernel_launch(void* const* d_in, const int* in_sizes, int n_in,
                              void* d_out, int out_size, void* d_ws,
                              size_t ws_size, hipStream_t stream) {
  const float* x      = (const float*)d_in[0];   // [B,T,D]   f32
  const float* w_qkv  = (const float*)d_in[1];   // [3D,D]    f32
  const float* w_out  = (const float*)d_in[2];   // [D,D]     f32
  const float* b_out  = (const float*)d_in[3];   // [D]       f32
  const float* memory = (const float*)d_in[4];   // [MEM,D]   f32

  char* ws = (char*)d_ws;
  bf16* q_ws   = (bf16*)(ws);                    // [32][2048][64]  8 MiB
  bf16* k_ws   = (bf16*)(ws + (8u << 20));       // [32][2048][64]  8 MiB
  bf16* vt_ws  = (bf16*)(ws + (16u << 20));      // [32][64][2048]  8 MiB
  bf16* mem_k  = (bf16*)(ws + (24u << 20));      // [16][512][64]   1 MiB
  bf16* mem_vt = (bf16*)(ws + (25u << 20));      // [1024][512]     1 MiB
  float* out = (float*)d_out;                    // f32 per reference

  char* outc = (char*)d_out;
  bf16* xb  = (bf16*)(outc);                     // 8 MiB scratch in d_out
  bf16* wqb = (bf16*)(outc + (8u << 20));        // 6 MiB scratch in d_out

  const bool big_ws = ws_size >= (28u << 20);
  bf16* wob = big_ws ? (bf16*)(ws + (26u << 20))   // private 2 MiB
                     : (bf16*)(ws + (8u << 20));   // aliases k_ws (post-attn)

  prep<<<dim3(big_ws ? 4352 : 3840), dim3(256), 0, stream>>>(
      x, w_qkv, memory, w_out, xb, wqb, mem_k, mem_vt, wob);
  gemm_bt<0, false, 128><<<dim3(24, 32), dim3(256), 0, stream>>>(
      xb, wqb, nullptr, q_ws, k_ws, vt_ws, nullptr, 1024);
  attn_kernel<<<dim3(512), dim3(512), 0, stream>>>(
      q_ws, k_ws, vt_ws, mem_k, mem_vt);
  if (!big_ws)
    conv_bf16<<<dim3(512), dim3(256), 0, stream>>>(w_out, wob);
  gemm_bt<1, true, 64><<<dim3(16, 32), dim3(256), 0, stream>>>(
      q_ws, wob, b_out, nullptr, nullptr, nullptr, out, 1024);
}

// Round 5
// 184.635 us; speedup vs baseline: 1.2094x; 1.0409x over previous
//
#include <hip/hip_runtime.h>
#include <hip/hip_bf16.h>
#include <stdint.h>

// Problem constants
#define B_   2
#define T_   2048
#define D_   1024
#define H_   16
#define HD_  64
#define MEM_ 512
#define KV_  (MEM_ + T_)   // 2560
#define NIT_ (KV_ / 64)    // 40 kv-tiles of 64

using bf16 = __bf16;
typedef __bf16 bf16x8 __attribute__((ext_vector_type(8)));
typedef float  f32x4  __attribute__((ext_vector_type(4)));
typedef short  s16x4  __attribute__((ext_vector_type(4)));
typedef short  s16x8  __attribute__((ext_vector_type(8)));

__device__ __forceinline__ f32x4 mfma16(bf16x8 a, bf16x8 b, f32x4 c) {
  return __builtin_amdgcn_mfma_f32_16x16x32_bf16(a, b, c, 0, 0, 0);
}

// Async global->LDS, 16B per lane (dest = wave-uniform base + lane*16).
__device__ __forceinline__ void gll16(const void* g, void* l) {
  __builtin_amdgcn_global_load_lds(
      (const __attribute__((address_space(1))) unsigned int*)g,
      (__attribute__((address_space(3))) unsigned int*)l, 16, 0, 0);
}

__device__ __forceinline__ unsigned short bf16_bits(float f) {
  bf16 h = (bf16)f;
  return __builtin_bit_cast(unsigned short, h);
}

__device__ __forceinline__ ushort4 pack4(f32x4 v) {
  ushort4 p;
  p.x = bf16_bits(v[0]); p.y = bf16_bits(v[1]);
  p.z = bf16_bits(v[2]); p.w = bf16_bits(v[3]);
  return p;
}

__device__ __forceinline__ bf16x8 cvt8(f32x4 a, f32x4 b) {
  bf16x8 r;
  r[0] = (bf16)a[0]; r[1] = (bf16)a[1]; r[2] = (bf16)a[2]; r[3] = (bf16)a[3];
  r[4] = (bf16)b[0]; r[5] = (bf16)b[1]; r[6] = (bf16)b[2]; r[7] = (bf16)b[3];
  return r;
}

// ---------------------------------------------------------------------------
// prep (fused): blk 0-2047 x conv | 2048-3583 w_qkv conv |
//   3584-3839 memory -> mem_k (row-coalesced) |
//   3840-4095 memory -> mem_vt (column pass: thread owns (d, m0..m0+7) so the
//     vt write is one contiguous 16B store; reads are lane-coalesced 256B) |
//   4096-4607 w_out conv (only when ws has room).
// ---------------------------------------------------------------------------
__global__ void prep(const float* __restrict__ x, const float* __restrict__ wq,
                     const float* __restrict__ memory,
                     const float* __restrict__ wout,
                     bf16* __restrict__ xb, bf16* __restrict__ wqb,
                     bf16* __restrict__ mem_k, bf16* __restrict__ mem_vt,
                     bf16* __restrict__ wob) {
  int blk = blockIdx.x;
  if (blk < 3584) {
    const float* s = (blk < 2048) ? x : wq;
    bf16* d = (blk < 2048) ? xb : wqb;
    size_t i = ((size_t)(blk < 2048 ? blk : blk - 2048) * 256 + threadIdx.x) * 8;
    f32x4 a = *(const f32x4*)(s + i);
    f32x4 b = *(const f32x4*)(s + i + 4);
    *(bf16x8*)(d + i) = cvt8(a, b);
  } else if (blk < 3840) {
    int idx8 = ((blk - 3584) * 256 + threadIdx.x) * 8;   // [0, 512*1024)
    int m = idx8 >> 10, d0 = idx8 & 1023;
    int hh = d0 >> 6, hd0 = d0 & 63;
    f32x4 a = *(const f32x4*)(memory + idx8);
    f32x4 b = *(const f32x4*)(memory + idx8 + 4);
    *(bf16x8*)&mem_k[((size_t)hh * MEM_ + m) * HD_ + hd0] = cvt8(a, b);
  } else if (blk < 4096) {
    int idx = (blk - 3840) * 256 + threadIdx.x;          // [0, 65536)
    int d = idx & 1023;
    int m0 = (idx >> 10) * 8;                            // 0..511 step 8
    bf16x8 r;
#pragma unroll
    for (int j = 0; j < 8; j++)
      r[j] = (bf16)memory[(size_t)(m0 + j) * D_ + d];
    *(bf16x8*)&mem_vt[(size_t)d * MEM_ + m0] = r;
  } else {
    size_t i = ((size_t)(blk - 4096) * 256 + threadIdx.x) * 8;
    f32x4 a = *(const f32x4*)(wout + i);
    f32x4 b = *(const f32x4*)(wout + i + 4);
    *(bf16x8*)(wob + i) = cvt8(a, b);
  }
}

// w_out conv fallback: runs AFTER attn (dest aliases k_ws, dead by then).
__global__ void conv_bf16(const float* __restrict__ s, bf16* __restrict__ d) {
  size_t i = ((size_t)blockIdx.x * 256 + threadIdx.x) * 8;
  f32x4 a = *(const f32x4*)(s + i);
  f32x4 b = *(const f32x4*)(s + i + 4);
  *(bf16x8*)(d + i) = cvt8(a, b);
}

// ---------------------------------------------------------------------------
// GEMM (B^T form): C[M,N] = A[M,K] * W[N,K]^T.  128 x NTILE tile, BK=64
// (32 MFMA per barrier pair), 4 waves (2x2).  Staging via global_load_lds w16
// into linear [rows][64] LDS; 16B-chunk XOR swizzle p = l ^ (row&7) applied
// on BOTH source chunk and ds_read (both-sides rule).  Bijective XCD swizzle
// on the block id (T1): consecutive blocks on one XCD share A panels, so
// panel re-reads hit the XCD-local L2 instead of refetching cross-XCD.
// EPI==0: scatter q/k -> [bh][t][64], v -> vt_ws[bh][hd][t] (transposed).
// EPI==1: bias add -> Cout [M][1024] f32.  APLANE: A is plane layout
//         [bh][t][64] (logical row m=b*T+t, col d=h*64+hd).
// ---------------------------------------------------------------------------
template <int EPI, bool APLANE, int NTILE>
__global__ __launch_bounds__(256, 3) void gemm_bt(
    const bf16* __restrict__ A, const bf16* __restrict__ W,
    const float* __restrict__ bias,
    bf16* __restrict__ q_ws, bf16* __restrict__ k_ws, bf16* __restrict__ vt_ws,
    float* __restrict__ Cout, int K) {
  constexpr int NF = NTILE / 32;        // n-frags per wave
  constexpr int NB = NTILE / 32;        // B-tile gll count
  __shared__ __align__(16) bf16 Als[128 * 64];
  __shared__ __align__(16) bf16 Bls[NTILE * 64];
  char* AB = (char*)Als;
  char* BB = (char*)Bls;
  // Bijective XCD swizzle (nwg % 8 == 0 for both launches).
  const int nwg = gridDim.x * gridDim.y;
  int lin = blockIdx.y * gridDim.x + blockIdx.x;
  lin = (lin & 7) * (nwg >> 3) + (lin >> 3);
  const int m0 = (lin / gridDim.x) * 128;
  const int n0 = (lin % gridDim.x) * NTILE;
  const int tid = threadIdx.x;
  const int w = tid >> 6;
  const int lane = tid & 63;
  const int lx = lane & 15;
  const int quad = lane >> 4;
  const int amb = (w & 1) * 64;
  const int bnb = (w >> 1) * (NTILE / 2);
  const int srow = tid >> 3;                        // 0..31 (+32g per gll)
  const int cs = (tid & 7) ^ (srow & 7);            // swizzled source chunk

  f32x4 acc[4][NF];
#pragma unroll
  for (int i = 0; i < 4; i++)
#pragma unroll
    for (int j = 0; j < NF; j++) acc[i][j] = (f32x4){0.f, 0.f, 0.f, 0.f};

  for (int k0 = 0; k0 < K; k0 += 64) {
    const bf16* pa[4];
#pragma unroll
    for (int g = 0; g < 4; g++) {
      int r = srow + 32 * g;
      if constexpr (APLANE) {
        int hh = k0 >> 6, hd = cs * 8;
        int mA = m0 + r;
        pa[g] = A + ((size_t)((mA >> 11) * H_ + hh) * T_ + (mA & 2047)) * HD_ + hd;
      } else {
        pa[g] = A + (size_t)(m0 + r) * K + k0 + cs * 8;
      }
    }
    const bf16* pb[NB];
#pragma unroll
    for (int g = 0; g < NB; g++)
      pb[g] = W + (size_t)(n0 + srow + 32 * g) * K + k0 + cs * 8;

    __syncthreads();   // prev iteration's LDS reads done
#pragma unroll
    for (int g = 0; g < 4; g++) gll16(pa[g], AB + g * 4096 + tid * 16);
#pragma unroll
    for (int g = 0; g < NB; g++) gll16(pb[g], BB + g * 4096 + tid * 16);
    __syncthreads();   // drains vmcnt -> tiles valid

    bf16x8 af[4][2], bfr[NF][2];
    const int rk = (lx & 7) << 4;   // read-side swizzle key (row&7 == lx&7)
#pragma unroll
    for (int mt = 0; mt < 4; mt++)
#pragma unroll
      for (int kh = 0; kh < 2; kh++)
        af[mt][kh] = *(const bf16x8*)(AB + (size_t)(amb + mt * 16 + lx) * 128 +
                                      ((quad * 16 + kh * 64) ^ rk));
#pragma unroll
    for (int nt = 0; nt < NF; nt++)
#pragma unroll
      for (int kh = 0; kh < 2; kh++)
        bfr[nt][kh] = *(const bf16x8*)(BB + (size_t)(bnb + nt * 16 + lx) * 128 +
                                       ((quad * 16 + kh * 64) ^ rk));
#pragma unroll
    for (int kh = 0; kh < 2; kh++)
#pragma unroll
      for (int mt = 0; mt < 4; mt++)
#pragma unroll
        for (int nt = 0; nt < NF; nt++)
          acc[mt][nt] = mfma16(af[mt][kh], bfr[nt][kh], acc[mt][nt]);
  }

  // Epilogue. C/D layout: row = quad*4+reg (m), col = lane&15 (n).
  if (EPI == 0) {
#pragma unroll
    for (int mt = 0; mt < 4; mt++) {
      int mbase = m0 + amb + mt * 16 + quad * 4;
      int b = mbase >> 11;        // T=2048
      int t = mbase & 2047;
#pragma unroll
      for (int nt = 0; nt < NF; nt++) {
        int col = n0 + bnb + nt * 16 + lx;     // [0,3072)
        int which = col >> 10;                 // 0=q 1=k 2=v
        int d = col & 1023;
        int hh = d >> 6, hdi = d & 63;
        int bh = b * H_ + hh;
        if (which == 0) {
#pragma unroll
          for (int r = 0; r < 4; r++)
            q_ws[((size_t)bh * T_ + t + r) * HD_ + hdi] = (bf16)acc[mt][nt][r];
        } else if (which == 1) {
#pragma unroll
          for (int r = 0; r < 4; r++)
            k_ws[((size_t)bh * T_ + t + r) * HD_ + hdi] = (bf16)acc[mt][nt][r];
        } else {
          // v^T: 4 consecutive t -> one 8B store
          *(ushort4*)&vt_ws[((size_t)bh * HD_ + hdi) * T_ + t] =
              pack4(acc[mt][nt]);
        }
      }
    }
  } else {
#pragma unroll
    for (int nt = 0; nt < NF; nt++) {
      int col = n0 + bnb + nt * 16 + lx;
      float bias_f = bias[col];
#pragma unroll
      for (int mt = 0; mt < 4; mt++) {
        int mbase = m0 + amb + mt * 16 + quad * 4;
#pragma unroll
        for (int r = 0; r < 4; r++)
          Cout[(size_t)(mbase + r) * D_ + col] = acc[mt][nt][r] + bias_f;
      }
    }
  }
}

// ---------------------------------------------------------------------------
// Flash attention (R3 structure, reverted from the 8-wave experiment):
// 4 waves x 32 q, 256 threads, double-buffered LDS + counted vmcnt, PV at
// full-rate k32 via the contraction-relabel trick.
// NEW: ones-MFMA row-sum — the softmax denominator sum_kv p is computed as
// 1^T . P by 4 extra MFMAs/iter (A = all-ones bf16) into osum[qg]; every
// lane's osum[qg][0] is the full denominator for its q-column (C rows of a
// constant-A MFMA are identical).  Removes 32 VALU adds/iter from the serial
// softmax chain and the epilogue cross-lane shuffles.
// 1 block = 128 q of one (b,h); kv-tile 64; grid 512; output in q_ws.
// ---------------------------------------------------------------------------
__global__ __launch_bounds__(256, 2) void attn_kernel(
    bf16* __restrict__ q_ws, const bf16* __restrict__ k_ws,
    const bf16* __restrict__ vt_ws, const bf16* __restrict__ mem_k,
    const bf16* __restrict__ mem_vt) {
  __shared__ __align__(16) bf16 Kls[2 * 64 * 64];
  __shared__ __align__(16) bf16 Vls[2 * 64 * 64];
  char* KB = (char*)Kls;
  char* VB = (char*)Vls;
  const int tid = threadIdx.x;
  const int w = tid >> 6;
  const int lane = tid & 63;
  const int lx = lane & 15;
  const int quad = lane >> 4;
  const int bh = blockIdx.x & 31;      // XCD-locality
  const int qt = blockIdx.x >> 5;      // 16 q-tiles of 128
  const int q0 = qt * 128 + w * 32;
  const int h = bh & 15;

  const int srow1 = tid >> 3;              // 0..31
  const int sc1 = (tid & 7) ^ (srow1 & 7); // pre-swizzled source chunk

  bf16* qbase = q_ws + ((size_t)bh * T_ + q0) * HD_;

  const bf16* kpl = k_ws + (size_t)bh * T_ * HD_;
  const bf16* vpl = vt_ws + (size_t)bh * HD_ * T_;
  const bf16* mkp = mem_k + (size_t)h * MEM_ * HD_;   // per-head plane
  const bf16* mvp = mem_vt + (size_t)h * HD_ * MEM_;

  // Stage kv-tile `it2` into LDS buffer `bi` (4 x gll16 per thread).
  auto stage = [&](int it2, int bi) {
    const int kv0 = it2 * 64;
    const bf16 *kp1, *kp2, *vp1, *vp2;
    if (kv0 < MEM_) {
      kp1 = mkp + (size_t)(kv0 + srow1) * HD_ + sc1 * 8;
      kp2 = kp1 + (size_t)32 * HD_;
      vp1 = mvp + (size_t)srow1 * MEM_ + kv0 + sc1 * 8;
      vp2 = vp1 + (size_t)32 * MEM_;
    } else {
      const int t0 = kv0 - MEM_;
      kp1 = kpl + (size_t)(t0 + srow1) * HD_ + sc1 * 8;
      kp2 = kp1 + (size_t)32 * HD_;
      vp1 = vpl + (size_t)srow1 * T_ + t0 + sc1 * 8;
      vp2 = vp1 + (size_t)32 * T_;
    }
    char* kb = KB + bi * 8192;
    char* vb = VB + bi * 8192;
    gll16(kp1, kb + tid * 16);
    gll16(kp2, kb + tid * 16 + 4096);
    gll16(vp1, vb + tid * 16);
    gll16(vp2, vb + tid * 16 + 4096);
  };

  // Q B-frags (k32); fold softmax scale AND log2(e) into Q:
  // s = (q*0.125*log2e) . k  ->  exp2(s) == exp(0.125 * q.k)
  const float QSCALE = 0.125f * 1.44269504089f;
  bf16x8 qf[2][2];
#pragma unroll
  for (int qg = 0; qg < 2; qg++)
#pragma unroll
    for (int hf = 0; hf < 2; hf++) {
      bf16x8 v = *(const bf16x8*)(qbase + (size_t)(qg * 16 + lx) * HD_ +
                                  hf * 32 + quad * 8);
#pragma unroll
      for (int i = 0; i < 8; i++)
        v[i] = (bf16)((float)v[i] * QSCALE);
      qf[qg][hf] = v;
    }

  bf16x8 ones;
#pragma unroll
  for (int i = 0; i < 8; i++) ones[i] = (bf16)1.0f;

  f32x4 o[4][2];
#pragma unroll
  for (int mt = 0; mt < 4; mt++)
#pragma unroll
    for (int qg = 0; qg < 2; qg++) o[mt][qg] = (f32x4){0.f, 0.f, 0.f, 0.f};
  f32x4 osum[2] = {(f32x4){0.f, 0.f, 0.f, 0.f}, (f32x4){0.f, 0.f, 0.f, 0.f}};

  stage(0, 0);   // prologue prefetch

  for (int it = 0; it < NIT_; it++) {
    const int cur = it & 1;
    if (it + 1 < NIT_) {
      stage(it + 1, cur ^ 1);
      asm volatile("s_waitcnt vmcnt(4)" ::: "memory");   // cur's 4 loads done
    } else {
      asm volatile("s_waitcnt vmcnt(0)" ::: "memory");
    }
    __builtin_amdgcn_s_barrier();        // all waves' cur parts landed
    __builtin_amdgcn_sched_barrier(0);

    const char* KBc = KB + cur * 8192;
    const char* VBc = VB + cur * 8192;
    const int sw = (lx & 7) << 4;   // read-side swizzle (row&7 == lx&7)
    f32x4 s[4][2];
    __builtin_amdgcn_s_setprio(1);
#pragma unroll
    for (int g = 0; g < 4; g++) {
      const char* kb = KBc + (size_t)(g * 16 + lx) * 128;
      bf16x8 ka0 = *(const bf16x8*)(kb + ((quad * 16) ^ sw));
      bf16x8 ka1 = *(const bf16x8*)(kb + ((64 + quad * 16) ^ sw));
#pragma unroll
      for (int qg = 0; qg < 2; qg++) {
        s[g][qg] = (f32x4){0.f, 0.f, 0.f, 0.f};
        s[g][qg] = mfma16(ka0, qf[qg][0], s[g][qg]);
        s[g][qg] = mfma16(ka1, qf[qg][1], s[g][qg]);
      }
    }
    __builtin_amdgcn_s_setprio(0);

    // softmax: p = exp2(s); pack straight into the k32 B-frag halves.
    s16x8 pk[2][2];   // [qg][pair]: elems 0-3 = group 2p, 4-7 = group 2p+1
#pragma unroll
    for (int qg = 0; qg < 2; qg++) {
#pragma unroll
      for (int g = 0; g < 4; g++) {
#pragma unroll
        for (int r = 0; r < 4; r++) {
          float p = __builtin_amdgcn_exp2f(s[g][qg][r]);  // raw v_exp_f32
          pk[qg][g >> 1][(g & 1) * 4 + r] = (short)bf16_bits(p);
        }
      }
    }

    __builtin_amdgcn_s_setprio(1);
#pragma unroll
    for (int mt = 0; mt < 4; mt++) {
      const char* vb = VBc + (size_t)(mt * 16 + lx) * 128;
#pragma unroll
      for (int p = 0; p < 2; p++) {
        // A-frag: V[d][kv] at kv-chunks p*32+quad*4 and p*32+16+quad*4
        s16x4 lo = *(const s16x4*)(vb + ((p * 64 + quad * 8) ^ sw));
        s16x4 hi = *(const s16x4*)(vb + ((p * 64 + 32 + quad * 8) ^ sw));
        s16x8 cat = __builtin_shufflevector(lo, hi, 0, 1, 2, 3, 4, 5, 6, 7);
        bf16x8 va = __builtin_bit_cast(bf16x8, cat);
#pragma unroll
        for (int qg = 0; qg < 2; qg++)
          o[mt][qg] = mfma16(va, __builtin_bit_cast(bf16x8, pk[qg][p]),
                             o[mt][qg]);
      }
    }
    // denominator: osum[qg] += 1^T . P  (all C rows identical)
#pragma unroll
    for (int p = 0; p < 2; p++)
#pragma unroll
      for (int qg = 0; qg < 2; qg++)
        osum[qg] = mfma16(ones, __builtin_bit_cast(bf16x8, pk[qg][p]),
                          osum[qg]);
    __builtin_amdgcn_s_setprio(0);

    __builtin_amdgcn_sched_barrier(0);
    __builtin_amdgcn_s_barrier();   // all waves done reading buf[cur]
  }

  float inv[2] = {1.f / osum[0][0], 1.f / osum[1][0]};

#pragma unroll
  for (int qg = 0; qg < 2; qg++) {
#pragma unroll
    for (int mt = 0; mt < 4; mt++) {
      f32x4 ov;
#pragma unroll
      for (int r = 0; r < 4; r++) ov[r] = o[mt][qg][r] * inv[qg];
      *(ushort4*)(qbase + (size_t)(qg * 16 + lx) * HD_ + mt * 16 + quad * 4)
          = pack4(ov);
    }
  }
}

// ---------------------------------------------------------------------------
// Scratch plan:
//   ws:    q_ws 0-8M | k_ws 8-16M | vt_ws 16-24M | mem_k 24-25M | mem_vt 25-26M
//          | wob 26-28M (only if ws_size >= 28M; else wob aliases k_ws and is
//          converted AFTER attn by the fallback conv kernel)
//   d_out: xb (bf16 x) 0-8M | wqb (bf16 w_qkv) 8-14M   [dead after gemm1;
//          gemm2 overwrites all of d_out with the real output]
// ---------------------------------------------------------------------------
extern "C" void kernel_launch(void* const* d_in, const int* in_sizes, int n_in,
                              void* d_out, int out_size, void* d_ws,
                              size_t ws_size, hipStream_t stream) {
  const float* x      = (const float*)d_in[0];   // [B,T,D]   f32
  const float* w_qkv  = (const float*)d_in[1];   // [3D,D]    f32
  const float* w_out  = (const float*)d_in[2];   // [D,D]     f32
  const float* b_out  = (const float*)d_in[3];   // [D]       f32
  const float* memory = (const float*)d_in[4];   // [MEM,D]   f32

  char* ws = (char*)d_ws;
  bf16* q_ws   = (bf16*)(ws);                    // [32][2048][64]  8 MiB
  bf16* k_ws   = (bf16*)(ws + (8u << 20));       // [32][2048][64]  8 MiB
  bf16* vt_ws  = (bf16*)(ws + (16u << 20));      // [32][64][2048]  8 MiB
  bf16* mem_k  = (bf16*)(ws + (24u << 20));      // [16][512][64]   1 MiB
  bf16* mem_vt = (bf16*)(ws + (25u << 20));      // [1024][512]     1 MiB
  float* out = (float*)d_out;                    // f32 per reference

  char* outc = (char*)d_out;
  bf16* xb  = (bf16*)(outc);                     // 8 MiB scratch in d_out
  bf16* wqb = (bf16*)(outc + (8u << 20));        // 6 MiB scratch in d_out

  const bool big_ws = ws_size >= (28u << 20);
  bf16* wob = big_ws ? (bf16*)(ws + (26u << 20))   // private 2 MiB
                     : (bf16*)(ws + (8u << 20));   // aliases k_ws (post-attn)

  prep<<<dim3(big_ws ? 4608 : 4096), dim3(256), 0, stream>>>(
      x, w_qkv, memory, w_out, xb, wqb, mem_k, mem_vt, wob);
  gemm_bt<0, false, 128><<<dim3(24, 32), dim3(256), 0, stream>>>(
      xb, wqb, nullptr, q_ws, k_ws, vt_ws, nullptr, 1024);
  attn_kernel<<<dim3(512), dim3(256), 0, stream>>>(
      q_ws, k_ws, vt_ws, mem_k, mem_vt);
  if (!big_ws)
    conv_bf16<<<dim3(512), dim3(256), 0, stream>>>(w_out, wob);
  gemm_bt<1, true, 64><<<dim3(16, 32), dim3(256), 0, stream>>>(
      q_ws, wob, b_out, nullptr, nullptr, nullptr, out, 1024);
}

// Round 6
// 179.455 us; speedup vs baseline: 1.2443x; 1.0289x over previous
//
#include <hip/hip_runtime.h>
#include <hip/hip_bf16.h>
#include <stdint.h>

// Problem constants
#define B_   2
#define T_   2048
#define D_   1024
#define H_   16
#define HD_  64
#define MEM_ 512
#define KV_  (MEM_ + T_)   // 2560
#define NIT_ (KV_ / 64)    // 40 kv-tiles of 64
#define NIT2_ (NIT_ / 2)   // 20 per kv-half

using bf16 = __bf16;
typedef __bf16 bf16x8 __attribute__((ext_vector_type(8)));
typedef float  f32x4  __attribute__((ext_vector_type(4)));
typedef short  s16x4  __attribute__((ext_vector_type(4)));
typedef short  s16x8  __attribute__((ext_vector_type(8)));

__device__ __forceinline__ f32x4 mfma16(bf16x8 a, bf16x8 b, f32x4 c) {
  return __builtin_amdgcn_mfma_f32_16x16x32_bf16(a, b, c, 0, 0, 0);
}

// Async global->LDS, 16B per lane (dest = wave-uniform base + lane*16).
__device__ __forceinline__ void gll16(const void* g, void* l) {
  __builtin_amdgcn_global_load_lds(
      (const __attribute__((address_space(1))) unsigned int*)g,
      (__attribute__((address_space(3))) unsigned int*)l, 16, 0, 0);
}

__device__ __forceinline__ unsigned short bf16_bits(float f) {
  bf16 h = (bf16)f;
  return __builtin_bit_cast(unsigned short, h);
}

__device__ __forceinline__ ushort4 pack4(f32x4 v) {
  ushort4 p;
  p.x = bf16_bits(v[0]); p.y = bf16_bits(v[1]);
  p.z = bf16_bits(v[2]); p.w = bf16_bits(v[3]);
  return p;
}

__device__ __forceinline__ bf16x8 cvt8(f32x4 a, f32x4 b) {
  bf16x8 r;
  r[0] = (bf16)a[0]; r[1] = (bf16)a[1]; r[2] = (bf16)a[2]; r[3] = (bf16)a[3];
  r[4] = (bf16)b[0]; r[5] = (bf16)b[1]; r[6] = (bf16)b[2]; r[7] = (bf16)b[3];
  return r;
}

// ---------------------------------------------------------------------------
// prep (fused): blk 0-2047 x conv | 2048-3583 w_qkv conv |
//   3584-3839 memory -> mem_k (row-coalesced) |
//   3840-4095 memory -> mem_vt (column pass: thread owns (d, m0..m0+7) so the
//     vt write is one contiguous 16B store; reads are lane-coalesced 256B) |
//   4096-4607 w_out conv (only when ws has room).
// ---------------------------------------------------------------------------
__global__ void prep(const float* __restrict__ x, const float* __restrict__ wq,
                     const float* __restrict__ memory,
                     const float* __restrict__ wout,
                     bf16* __restrict__ xb, bf16* __restrict__ wqb,
                     bf16* __restrict__ mem_k, bf16* __restrict__ mem_vt,
                     bf16* __restrict__ wob) {
  int blk = blockIdx.x;
  if (blk < 3584) {
    const float* s = (blk < 2048) ? x : wq;
    bf16* d = (blk < 2048) ? xb : wqb;
    size_t i = ((size_t)(blk < 2048 ? blk : blk - 2048) * 256 + threadIdx.x) * 8;
    f32x4 a = *(const f32x4*)(s + i);
    f32x4 b = *(const f32x4*)(s + i + 4);
    *(bf16x8*)(d + i) = cvt8(a, b);
  } else if (blk < 3840) {
    int idx8 = ((blk - 3584) * 256 + threadIdx.x) * 8;   // [0, 512*1024)
    int m = idx8 >> 10, d0 = idx8 & 1023;
    int hh = d0 >> 6, hd0 = d0 & 63;
    f32x4 a = *(const f32x4*)(memory + idx8);
    f32x4 b = *(const f32x4*)(memory + idx8 + 4);
    *(bf16x8*)&mem_k[((size_t)hh * MEM_ + m) * HD_ + hd0] = cvt8(a, b);
  } else if (blk < 4096) {
    int idx = (blk - 3840) * 256 + threadIdx.x;          // [0, 65536)
    int d = idx & 1023;
    int m0 = (idx >> 10) * 8;                            // 0..511 step 8
    bf16x8 r;
#pragma unroll
    for (int j = 0; j < 8; j++)
      r[j] = (bf16)memory[(size_t)(m0 + j) * D_ + d];
    *(bf16x8*)&mem_vt[(size_t)d * MEM_ + m0] = r;
  } else {
    size_t i = ((size_t)(blk - 4096) * 256 + threadIdx.x) * 8;
    f32x4 a = *(const f32x4*)(wout + i);
    f32x4 b = *(const f32x4*)(wout + i + 4);
    *(bf16x8*)(wob + i) = cvt8(a, b);
  }
}

// w_out conv fallback: runs AFTER attn (dest aliases k_ws, dead by then).
__global__ void conv_bf16(const float* __restrict__ s, bf16* __restrict__ d) {
  size_t i = ((size_t)blockIdx.x * 256 + threadIdx.x) * 8;
  f32x4 a = *(const f32x4*)(s + i);
  f32x4 b = *(const f32x4*)(s + i + 4);
  *(bf16x8*)(d + i) = cvt8(a, b);
}

// ---------------------------------------------------------------------------
// GEMM (B^T form): C[M,N] = A[M,K] * W[N,K]^T.  128 x NTILE tile, BK=64
// (32 MFMA per barrier pair), 4 waves (2x2).  Staging via global_load_lds w16
// into linear [rows][64] LDS; 16B-chunk XOR swizzle p = l ^ (row&7) applied
// on BOTH source chunk and ds_read (both-sides rule).  Bijective XCD swizzle
// on the block id (T1).
// EPI==0: scatter q/k -> [bh][t][64], v -> vt_ws[bh][hd][t] (transposed).
// EPI==1: bias add -> Cout [M][1024] f32.  APLANE: A is plane layout
//         [bh][t][64] (logical row m=b*T+t, col d=h*64+hd).
// ---------------------------------------------------------------------------
template <int EPI, bool APLANE, int NTILE>
__global__ __launch_bounds__(256, 3) void gemm_bt(
    const bf16* __restrict__ A, const bf16* __restrict__ W,
    const float* __restrict__ bias,
    bf16* __restrict__ q_ws, bf16* __restrict__ k_ws, bf16* __restrict__ vt_ws,
    float* __restrict__ Cout, int K) {
  constexpr int NF = NTILE / 32;        // n-frags per wave
  constexpr int NB = NTILE / 32;        // B-tile gll count
  __shared__ __align__(16) bf16 Als[128 * 64];
  __shared__ __align__(16) bf16 Bls[NTILE * 64];
  char* AB = (char*)Als;
  char* BB = (char*)Bls;
  // Bijective XCD swizzle (nwg % 8 == 0 for both launches).
  const int nwg = gridDim.x * gridDim.y;
  int lin = blockIdx.y * gridDim.x + blockIdx.x;
  lin = (lin & 7) * (nwg >> 3) + (lin >> 3);
  const int m0 = (lin / gridDim.x) * 128;
  const int n0 = (lin % gridDim.x) * NTILE;
  const int tid = threadIdx.x;
  const int w = tid >> 6;
  const int lane = tid & 63;
  const int lx = lane & 15;
  const int quad = lane >> 4;
  const int amb = (w & 1) * 64;
  const int bnb = (w >> 1) * (NTILE / 2);
  const int srow = tid >> 3;                        // 0..31 (+32g per gll)
  const int cs = (tid & 7) ^ (srow & 7);            // swizzled source chunk

  f32x4 acc[4][NF];
#pragma unroll
  for (int i = 0; i < 4; i++)
#pragma unroll
    for (int j = 0; j < NF; j++) acc[i][j] = (f32x4){0.f, 0.f, 0.f, 0.f};

  for (int k0 = 0; k0 < K; k0 += 64) {
    const bf16* pa[4];
#pragma unroll
    for (int g = 0; g < 4; g++) {
      int r = srow + 32 * g;
      if constexpr (APLANE) {
        int hh = k0 >> 6, hd = cs * 8;
        int mA = m0 + r;
        pa[g] = A + ((size_t)((mA >> 11) * H_ + hh) * T_ + (mA & 2047)) * HD_ + hd;
      } else {
        pa[g] = A + (size_t)(m0 + r) * K + k0 + cs * 8;
      }
    }
    const bf16* pb[NB];
#pragma unroll
    for (int g = 0; g < NB; g++)
      pb[g] = W + (size_t)(n0 + srow + 32 * g) * K + k0 + cs * 8;

    __syncthreads();   // prev iteration's LDS reads done
#pragma unroll
    for (int g = 0; g < 4; g++) gll16(pa[g], AB + g * 4096 + tid * 16);
#pragma unroll
    for (int g = 0; g < NB; g++) gll16(pb[g], BB + g * 4096 + tid * 16);
    __syncthreads();   // drains vmcnt -> tiles valid

    bf16x8 af[4][2], bfr[NF][2];
    const int rk = (lx & 7) << 4;   // read-side swizzle key (row&7 == lx&7)
#pragma unroll
    for (int mt = 0; mt < 4; mt++)
#pragma unroll
      for (int kh = 0; kh < 2; kh++)
        af[mt][kh] = *(const bf16x8*)(AB + (size_t)(amb + mt * 16 + lx) * 128 +
                                      ((quad * 16 + kh * 64) ^ rk));
#pragma unroll
    for (int nt = 0; nt < NF; nt++)
#pragma unroll
      for (int kh = 0; kh < 2; kh++)
        bfr[nt][kh] = *(const bf16x8*)(BB + (size_t)(bnb + nt * 16 + lx) * 128 +
                                       ((quad * 16 + kh * 64) ^ rk));
#pragma unroll
    for (int kh = 0; kh < 2; kh++)
#pragma unroll
      for (int mt = 0; mt < 4; mt++)
#pragma unroll
        for (int nt = 0; nt < NF; nt++)
          acc[mt][nt] = mfma16(af[mt][kh], bfr[nt][kh], acc[mt][nt]);
  }

  // Epilogue. C/D layout: row = quad*4+reg (m), col = lane&15 (n).
  if (EPI == 0) {
#pragma unroll
    for (int mt = 0; mt < 4; mt++) {
      int mbase = m0 + amb + mt * 16 + quad * 4;
      int b = mbase >> 11;        // T=2048
      int t = mbase & 2047;
#pragma unroll
      for (int nt = 0; nt < NF; nt++) {
        int col = n0 + bnb + nt * 16 + lx;     // [0,3072)
        int which = col >> 10;                 // 0=q 1=k 2=v
        int d = col & 1023;
        int hh = d >> 6, hdi = d & 63;
        int bh = b * H_ + hh;
        if (which == 0) {
#pragma unroll
          for (int r = 0; r < 4; r++)
            q_ws[((size_t)bh * T_ + t + r) * HD_ + hdi] = (bf16)acc[mt][nt][r];
        } else if (which == 1) {
#pragma unroll
          for (int r = 0; r < 4; r++)
            k_ws[((size_t)bh * T_ + t + r) * HD_ + hdi] = (bf16)acc[mt][nt][r];
        } else {
          // v^T: 4 consecutive t -> one 8B store
          *(ushort4*)&vt_ws[((size_t)bh * HD_ + hdi) * T_ + t] =
              pack4(acc[mt][nt]);
        }
      }
    }
  } else {
#pragma unroll
    for (int nt = 0; nt < NF; nt++) {
      int col = n0 + bnb + nt * 16 + lx;
      float bias_f = bias[col];
#pragma unroll
      for (int mt = 0; mt < 4; mt++) {
        int mbase = m0 + amb + mt * 16 + quad * 4;
#pragma unroll
        for (int r = 0; r < 4; r++)
          Cout[(size_t)(mbase + r) * D_ + col] = acc[mt][nt][r] + bias_f;
      }
    }
  }
}

// ---------------------------------------------------------------------------
// Flash attention, IN-BLOCK KV-SPLIT x2:
// 512 threads = 2 kv-halves x 4 waves.  Both halves own the SAME 128 q rows;
// half wh processes kv-tiles [wh*20, wh*20+20) with its OWN double-buffered
// 32 KB LDS pair (64 KB total -> still 2 blocks/CU, but 16 waves/CU = 4/SIMD,
// double the old TLP).  Per-wave q stays 32 (avoids the R4 failure: LDS-read
// per output did NOT increase), total staging bytes unchanged, no extra
// launches.  No running max -> merge is LINEAR: half 1 dumps o-partials +
// denominators into the dead K/V LDS, half 0 adds, normalizes, stores.
// PV at full-rate k32 (contraction relabel) + ones-MFMA row-sum as in R5.
// 1 block = 128 q of one (b,h); grid 512; output in q_ws.
// ---------------------------------------------------------------------------
__global__ __launch_bounds__(512, 4) void attn_kernel(
    bf16* __restrict__ q_ws, const bf16* __restrict__ k_ws,
    const bf16* __restrict__ vt_ws, const bf16* __restrict__ mem_k,
    const bf16* __restrict__ mem_vt) {
  __shared__ __align__(16) bf16 Kls[2 * 2 * 64 * 64];   // [half][buf][64][64]
  __shared__ __align__(16) bf16 Vls[2 * 2 * 64 * 64];
  char* KB = (char*)Kls;
  char* VB = (char*)Vls;
  const int tid = threadIdx.x;         // 0..511
  const int wh = tid >> 8;             // kv-half
  const int t2 = tid & 255;
  const int w = t2 >> 6;               // wave within half
  const int lane = tid & 63;
  const int lx = lane & 15;
  const int quad = lane >> 4;
  const int bh = blockIdx.x & 31;      // XCD-locality
  const int qt = blockIdx.x >> 5;      // 16 q-tiles of 128
  const int q0 = qt * 128 + w * 32;
  const int h = bh & 15;

  const int srow1 = t2 >> 3;               // 0..31
  const int sc1 = (t2 & 7) ^ (srow1 & 7);  // pre-swizzled source chunk

  char* KBh = KB + wh * 16384;
  char* VBh = VB + wh * 16384;

  bf16* qbase = q_ws + ((size_t)bh * T_ + q0) * HD_;

  const bf16* kpl = k_ws + (size_t)bh * T_ * HD_;
  const bf16* vpl = vt_ws + (size_t)bh * HD_ * T_;
  const bf16* mkp = mem_k + (size_t)h * MEM_ * HD_;   // per-head plane
  const bf16* mvp = mem_vt + (size_t)h * HD_ * MEM_;

  // Stage this half's kv-tile `it2` (local index) into buffer `bi`.
  auto stage = [&](int it2, int bi) {
    const int kv0 = (wh * NIT2_ + it2) * 64;
    const bf16 *kp1, *kp2, *vp1, *vp2;
    if (kv0 < MEM_) {
      kp1 = mkp + (size_t)(kv0 + srow1) * HD_ + sc1 * 8;
      kp2 = kp1 + (size_t)32 * HD_;
      vp1 = mvp + (size_t)srow1 * MEM_ + kv0 + sc1 * 8;
      vp2 = vp1 + (size_t)32 * MEM_;
    } else {
      const int t0 = kv0 - MEM_;
      kp1 = kpl + (size_t)(t0 + srow1) * HD_ + sc1 * 8;
      kp2 = kp1 + (size_t)32 * HD_;
      vp1 = vpl + (size_t)srow1 * T_ + t0 + sc1 * 8;
      vp2 = vp1 + (size_t)32 * T_;
    }
    char* kb = KBh + bi * 8192;
    char* vb = VBh + bi * 8192;
    gll16(kp1, kb + t2 * 16);
    gll16(kp2, kb + t2 * 16 + 4096);
    gll16(vp1, vb + t2 * 16);
    gll16(vp2, vb + t2 * 16 + 4096);
  };

  // Q B-frags (k32); fold softmax scale AND log2(e) into Q:
  // s = (q*0.125*log2e) . k  ->  exp2(s) == exp(0.125 * q.k)
  const float QSCALE = 0.125f * 1.44269504089f;
  bf16x8 qf[2][2];
#pragma unroll
  for (int qg = 0; qg < 2; qg++)
#pragma unroll
    for (int hf = 0; hf < 2; hf++) {
      bf16x8 v = *(const bf16x8*)(qbase + (size_t)(qg * 16 + lx) * HD_ +
                                  hf * 32 + quad * 8);
#pragma unroll
      for (int i = 0; i < 8; i++)
        v[i] = (bf16)((float)v[i] * QSCALE);
      qf[qg][hf] = v;
    }

  bf16x8 ones;
#pragma unroll
  for (int i = 0; i < 8; i++) ones[i] = (bf16)1.0f;

  f32x4 o[4][2];
#pragma unroll
  for (int mt = 0; mt < 4; mt++)
#pragma unroll
    for (int qg = 0; qg < 2; qg++) o[mt][qg] = (f32x4){0.f, 0.f, 0.f, 0.f};
  f32x4 osum[2] = {(f32x4){0.f, 0.f, 0.f, 0.f}, (f32x4){0.f, 0.f, 0.f, 0.f}};

  stage(0, 0);   // prologue prefetch

  for (int it = 0; it < NIT2_; it++) {
    const int cur = it & 1;
    if (it + 1 < NIT2_) {
      stage(it + 1, cur ^ 1);
      asm volatile("s_waitcnt vmcnt(4)" ::: "memory");   // cur's 4 loads done
    } else {
      asm volatile("s_waitcnt vmcnt(0)" ::: "memory");
    }
    __builtin_amdgcn_s_barrier();        // all waves' cur parts landed
    __builtin_amdgcn_sched_barrier(0);

    const char* KBc = KBh + cur * 8192;
    const char* VBc = VBh + cur * 8192;
    const int sw = (lx & 7) << 4;   // read-side swizzle (row&7 == lx&7)
    f32x4 s[4][2];
    __builtin_amdgcn_s_setprio(1);
#pragma unroll
    for (int g = 0; g < 4; g++) {
      const char* kb = KBc + (size_t)(g * 16 + lx) * 128;
      bf16x8 ka0 = *(const bf16x8*)(kb + ((quad * 16) ^ sw));
      bf16x8 ka1 = *(const bf16x8*)(kb + ((64 + quad * 16) ^ sw));
#pragma unroll
      for (int qg = 0; qg < 2; qg++) {
        s[g][qg] = (f32x4){0.f, 0.f, 0.f, 0.f};
        s[g][qg] = mfma16(ka0, qf[qg][0], s[g][qg]);
        s[g][qg] = mfma16(ka1, qf[qg][1], s[g][qg]);
      }
    }
    __builtin_amdgcn_s_setprio(0);

    // softmax: p = exp2(s); pack straight into the k32 B-frag halves.
    s16x8 pk[2][2];   // [qg][pair]: elems 0-3 = group 2p, 4-7 = group 2p+1
#pragma unroll
    for (int qg = 0; qg < 2; qg++) {
#pragma unroll
      for (int g = 0; g < 4; g++) {
#pragma unroll
        for (int r = 0; r < 4; r++) {
          float p = __builtin_amdgcn_exp2f(s[g][qg][r]);  // raw v_exp_f32
          pk[qg][g >> 1][(g & 1) * 4 + r] = (short)bf16_bits(p);
        }
      }
    }

    __builtin_amdgcn_s_setprio(1);
#pragma unroll
    for (int mt = 0; mt < 4; mt++) {
      const char* vb = VBc + (size_t)(mt * 16 + lx) * 128;
#pragma unroll
      for (int p = 0; p < 2; p++) {
        // A-frag: V[d][kv] at kv-chunks p*32+quad*4 and p*32+16+quad*4
        s16x4 lo = *(const s16x4*)(vb + ((p * 64 + quad * 8) ^ sw));
        s16x4 hi = *(const s16x4*)(vb + ((p * 64 + 32 + quad * 8) ^ sw));
        s16x8 cat = __builtin_shufflevector(lo, hi, 0, 1, 2, 3, 4, 5, 6, 7);
        bf16x8 va = __builtin_bit_cast(bf16x8, cat);
#pragma unroll
        for (int qg = 0; qg < 2; qg++)
          o[mt][qg] = mfma16(va, __builtin_bit_cast(bf16x8, pk[qg][p]),
                             o[mt][qg]);
      }
    }
    // denominator: osum[qg] += 1^T . P  (all C rows identical)
#pragma unroll
    for (int p = 0; p < 2; p++)
#pragma unroll
      for (int qg = 0; qg < 2; qg++)
        osum[qg] = mfma16(ones, __builtin_bit_cast(bf16x8, pk[qg][p]),
                          osum[qg]);
    __builtin_amdgcn_s_setprio(0);

    __builtin_amdgcn_sched_barrier(0);
    __builtin_amdgcn_s_barrier();   // all waves done reading buf[cur]
  }

  // ---- linear merge of the two kv-halves through the (now dead) K/V LDS ---
  float* OS = (float*)KB;          // 32 KB: half-1 o partials
  float* OSS = (float*)VB;         // 2 KB: half-1 denominators
  if (wh == 1) {
    float* dst = OS + t2 * 32;
#pragma unroll
    for (int mt = 0; mt < 4; mt++)
#pragma unroll
      for (int qg = 0; qg < 2; qg++) {
        int c = mt * 2 + qg;   // chunk 0..7, XOR-spread across banks
        *(f32x4*)(dst + ((c ^ (t2 & 7)) * 4)) = o[mt][qg];
      }
    OSS[t2 * 2 + 0] = osum[0][0];
    OSS[t2 * 2 + 1] = osum[1][0];
  }
  __syncthreads();
  if (wh == 0) {
    const float* src = OS + t2 * 32;
    float inv[2] = {1.f / (osum[0][0] + OSS[t2 * 2 + 0]),
                    1.f / (osum[1][0] + OSS[t2 * 2 + 1])};
#pragma unroll
    for (int qg = 0; qg < 2; qg++) {
#pragma unroll
      for (int mt = 0; mt < 4; mt++) {
        int c = mt * 2 + qg;
        f32x4 po = *(const f32x4*)(src + ((c ^ (t2 & 7)) * 4));
        f32x4 ov;
#pragma unroll
        for (int r = 0; r < 4; r++) ov[r] = (o[mt][qg][r] + po[r]) * inv[qg];
        *(ushort4*)(qbase + (size_t)(qg * 16 + lx) * HD_ + mt * 16 + quad * 4)
            = pack4(ov);
      }
    }
  }
}

// ---------------------------------------------------------------------------
// Scratch plan:
//   ws:    q_ws 0-8M | k_ws 8-16M | vt_ws 16-24M | mem_k 24-25M | mem_vt 25-26M
//          | wob 26-28M (only if ws_size >= 28M; else wob aliases k_ws and is
//          converted AFTER attn by the fallback conv kernel)
//   d_out: xb (bf16 x) 0-8M | wqb (bf16 w_qkv) 8-14M   [dead after gemm1;
//          gemm2 overwrites all of d_out with the real output]
// ---------------------------------------------------------------------------
extern "C" void kernel_launch(void* const* d_in, const int* in_sizes, int n_in,
                              void* d_out, int out_size, void* d_ws,
                              size_t ws_size, hipStream_t stream) {
  const float* x      = (const float*)d_in[0];   // [B,T,D]   f32
  const float* w_qkv  = (const float*)d_in[1];   // [3D,D]    f32
  const float* w_out  = (const float*)d_in[2];   // [D,D]     f32
  const float* b_out  = (const float*)d_in[3];   // [D]       f32
  const float* memory = (const float*)d_in[4];   // [MEM,D]   f32

  char* ws = (char*)d_ws;
  bf16* q_ws   = (bf16*)(ws);                    // [32][2048][64]  8 MiB
  bf16* k_ws   = (bf16*)(ws + (8u << 20));       // [32][2048][64]  8 MiB
  bf16* vt_ws  = (bf16*)(ws + (16u << 20));      // [32][64][2048]  8 MiB
  bf16* mem_k  = (bf16*)(ws + (24u << 20));      // [16][512][64]   1 MiB
  bf16* mem_vt = (bf16*)(ws + (25u << 20));      // [1024][512]     1 MiB
  float* out = (float*)d_out;                    // f32 per reference

  char* outc = (char*)d_out;
  bf16* xb  = (bf16*)(outc);                     // 8 MiB scratch in d_out
  bf16* wqb = (bf16*)(outc + (8u << 20));        // 6 MiB scratch in d_out

  const bool big_ws = ws_size >= (28u << 20);
  bf16* wob = big_ws ? (bf16*)(ws + (26u << 20))   // private 2 MiB
                     : (bf16*)(ws + (8u << 20));   // aliases k_ws (post-attn)

  prep<<<dim3(big_ws ? 4608 : 4096), dim3(256), 0, stream>>>(
      x, w_qkv, memory, w_out, xb, wqb, mem_k, mem_vt, wob);
  gemm_bt<0, false, 128><<<dim3(24, 32), dim3(256), 0, stream>>>(
      xb, wqb, nullptr, q_ws, k_ws, vt_ws, nullptr, 1024);
  attn_kernel<<<dim3(512), dim3(512), 0, stream>>>(
      q_ws, k_ws, vt_ws, mem_k, mem_vt);
  if (!big_ws)
    conv_bf16<<<dim3(512), dim3(256), 0, stream>>>(w_out, wob);
  gemm_bt<1, true, 64><<<dim3(16, 32), dim3(256), 0, stream>>>(
      q_ws, wob, b_out, nullptr, nullptr, nullptr, out, 1024);
}